// Round 5
// baseline (48040.692 us; speedup 1.0000x reference)
//
#include <hip/hip_runtime.h>

static constexpr int KN  = 256;   // codebook entries
static constexpr int DD  = 384;   // feature dim
static constexpr int DD4 = 96;    // DD/4
static constexpr int TM  = 64;    // rows per block
static constexpr int DK  = 32;    // D-chunk per LDS stage
#define FLAG_MARGIN 0.005f

// ======== numpy-fp32 emulation helpers (VALIDATED in round 4 — do not touch) ====

// np.sum(p*p, axis=-1), n=384: pairwise 384->(96+96)+(96+96);
// 96-block = 8 scalar accumulators, tree ((r0+r1)+(r2+r3))+((r4+r5)+(r6+r7))
__device__ __forceinline__ float emu_sq_pairwise384(const float* __restrict__ p) {
  float S[4];
#pragma unroll
  for (int blk = 0; blk < 4; ++blk) {
    const float* b = p + blk * 96;
    float r[8];
#pragma unroll
    for (int l = 0; l < 8; ++l) r[l] = __fmul_rn(b[l], b[l]);
    for (int j = 8; j < 96; j += 8) {
#pragma unroll
      for (int l = 0; l < 8; ++l) r[l] = __fadd_rn(r[l], __fmul_rn(b[j + l], b[j + l]));
    }
    float t1 = __fadd_rn(__fadd_rn(r[0], r[1]), __fadd_rn(r[2], r[3]));
    float t2 = __fadd_rn(__fadd_rn(r[4], r[5]), __fadd_rn(r[6], r[7]));
    S[blk] = __fadd_rn(t1, t2);
  }
  return __fadd_rn(__fadd_rn(S[0], S[1]), __fadd_rn(S[2], S[3]));
}

// Modern numpy einsum sum_of_products_contig_two, SSE baseline:
// 4 vector accumulators x 4 lanes, muladd = mul+add (2 roundings),
// combine (acc0+acc1)+(acc2+acc3), then SSE3 hadd tree (w0+w1)+(w2+w3).
__device__ __forceinline__ float emu_dot384_np(const float* __restrict__ x,
                                               const float* __restrict__ c) {
  float s[16];
#pragma unroll
  for (int t = 0; t < 16; ++t) s[t] = 0.f;
  for (int j = 0; j < 384; j += 16) {
#pragma unroll
    for (int t = 0; t < 16; ++t)
      s[t] = __fadd_rn(__fmul_rn(x[j + t], c[j + t]), s[t]);
  }
  float w0 = __fadd_rn(__fadd_rn(s[0], s[4]), __fadd_rn(s[8],  s[12]));
  float w1 = __fadd_rn(__fadd_rn(s[1], s[5]), __fadd_rn(s[9],  s[13]));
  float w2 = __fadd_rn(__fadd_rn(s[2], s[6]), __fadd_rn(s[10], s[14]));
  float w3 = __fadd_rn(__fadd_rn(s[3], s[7]), __fadd_rn(s[11], s[15]));
  return __fadd_rn(__fadd_rn(w0, w1), __fadd_rn(w2, w3));
}

// ---------------- codebook squared norms: exact numpy values ----------------
__global__ void cb_norms_kernel(const float* __restrict__ cb0,
                                const float* __restrict__ cb1,
                                const float* __restrict__ cb2,
                                float* __restrict__ e2,
                                double* __restrict__ delta) {
  int l = blockIdx.x;
  int k = threadIdx.x;
  const float* cb = (l == 0) ? cb0 : ((l == 1) ? cb1 : cb2);
  e2[l * KN + k] = emu_sq_pairwise384(cb + (size_t)k * DD);
  if (k == 0) delta[l] = 0.0;   // zero the loss-delta accumulators each call
}

// ---------------- phase 1: GEMM + argmin + flag (NO emu code here) ----------
// Block: 256 threads. Tile: TM=64 rows x all K=256 cols.
// Thread (rg,cg): rg=tid>>4 owns rows rg*4..rg*4+3; cg=tid&15 owns cols cg+16*c.
__global__ __launch_bounds__(256, 3) void vq_main(
    const float* __restrict__ X,
    const float* __restrict__ CB,
    const float* __restrict__ E2,
    float* __restrict__ Q,
    float* __restrict__ IDXO,
    unsigned char* __restrict__ FLAG,
    double* __restrict__ PART)
{
  __shared__ float As[TM][36];
  __shared__ float Bs[KN][36];
  __shared__ int idx_s[TM];
  __shared__ double wred[4];

  const int tid = threadIdx.x;
  const int rg = tid >> 4;
  const int cg = tid & 15;
  const size_t row0 = (size_t)blockIdx.x * TM;

  const float4* X4  = reinterpret_cast<const float4*>(X);
  const float4* CB4 = reinterpret_cast<const float4*>(CB);
  float4* Q4 = reinterpret_cast<float4*>(Q);

  float acc[4][16];
#pragma unroll
  for (int j = 0; j < 4; ++j)
#pragma unroll
    for (int c = 0; c < 16; ++c) acc[j][c] = 0.f;

  for (int d0 = 0; d0 < DD; d0 += DK) {
    const int dq = d0 >> 2;
#pragma unroll
    for (int s = 0; s < 2; ++s) {
      int i = tid + s * 256;
      int r = i >> 3, f = i & 7;
      float4 v = X4[(row0 + (size_t)r) * DD4 + dq + f];
      *reinterpret_cast<float4*>(&As[r][4 * f]) = v;
    }
#pragma unroll
    for (int s = 0; s < 8; ++s) {
      int i = tid + s * 256;
      int k = i >> 3, f = i & 7;
      *reinterpret_cast<float4*>(&Bs[k][4 * f]) = CB4[(size_t)k * DD4 + dq + f];
    }
    __syncthreads();

#pragma unroll
    for (int d = 0; d < DK; d += 4) {
      float4 a0 = *reinterpret_cast<const float4*>(&As[rg * 4 + 0][d]);
      float4 a1 = *reinterpret_cast<const float4*>(&As[rg * 4 + 1][d]);
      float4 a2 = *reinterpret_cast<const float4*>(&As[rg * 4 + 2][d]);
      float4 a3 = *reinterpret_cast<const float4*>(&As[rg * 4 + 3][d]);
#pragma unroll
      for (int c = 0; c < 16; ++c) {
        float4 b = *reinterpret_cast<const float4*>(&Bs[cg + 16 * c][d]);
        acc[0][c] += a0.x * b.x + a0.y * b.y + a0.z * b.z + a0.w * b.w;
        acc[1][c] += a1.x * b.x + a1.y * b.y + a1.z * b.z + a1.w * b.w;
        acc[2][c] += a2.x * b.x + a2.y * b.y + a2.z * b.z + a2.w * b.w;
        acc[3][c] += a3.x * b.x + a3.y * b.y + a3.z * b.z + a3.w * b.w;
      }
    }
    __syncthreads();
  }

  float my_e2[16];
#pragma unroll
  for (int c = 0; c < 16; ++c) my_e2[c] = E2[cg + 16 * c];

#pragma unroll 1
  for (int j = 0; j < 4; ++j) {
    // ---- pass 1: global min (first-index tie-break) ----
    float b1 = 1e30f; int i1 = 0x7fffffff;
#pragma unroll
    for (int c = 0; c < 16; ++c) {
      int col = cg + 16 * c;
      float sc = my_e2[c] - 2.0f * acc[j][c];
      if (sc < b1 || (sc == b1 && col < i1)) { b1 = sc; i1 = col; }
    }
#pragma unroll
    for (int m = 1; m < 16; m <<= 1) {
      float ob = __shfl_xor(b1, m);
      int   oi = __shfl_xor(i1, m);
      if (ob < b1 || (ob == b1 && oi < i1)) { b1 = ob; i1 = oi; }
    }
    // ---- pass 2: runner-up value (for the flag test) ----
    float b2 = 1e30f;
#pragma unroll
    for (int c = 0; c < 16; ++c) {
      int col = cg + 16 * c;
      if (col == i1) continue;
      float sc = my_e2[c] - 2.0f * acc[j][c];
      if (sc < b2) b2 = sc;
    }
#pragma unroll
    for (int m = 1; m < 16; m <<= 1) {
      float ob = __shfl_xor(b2, m);
      if (ob < b2) b2 = ob;
    }

    if (cg == 0) {
      idx_s[rg * 4 + j] = i1;
      FLAG[row0 + (size_t)(rg * 4 + j)] = (b2 - b1 < FLAG_MARGIN) ? 1 : 0;
    }
  }
  __syncthreads();

  // ---- outputs: idx (as float), q = cb[idx], loss partial ----
  if (tid < TM) IDXO[row0 + tid] = (float)idx_s[tid];

  float lsum = 0.f;
  for (int i = tid; i < TM * DD4; i += 256) {
    int r = i / DD4;
    int c = i - r * DD4;
    int k = idx_s[r];
    float4 qv = CB4[(size_t)k * DD4 + c];
    float4 xv = X4[(row0 + (size_t)r) * DD4 + c];
    float dx = qv.x - xv.x, dy = qv.y - xv.y, dz = qv.z - xv.z, dw = qv.w - xv.w;
    lsum += dx * dx + dy * dy + dz * dz + dw * dw;
    Q4[(row0 + (size_t)r) * DD4 + c] = qv;
  }
#pragma unroll
  for (int m = 1; m < 64; m <<= 1) lsum += __shfl_xor(lsum, m);
  if ((tid & 63) == 0) wred[tid >> 6] = (double)lsum;
  __syncthreads();
  if (tid == 0) PART[blockIdx.x] = wred[0] + wred[1] + wred[2] + wred[3];
}

// ---------------- phase 2: numpy-exact refine of flagged rows ----------------
// One wave per flagged row; waves scan flag bytes 64-at-a-time via ballot.
__global__ __launch_bounds__(256) void vq_refine(
    const float* __restrict__ X,
    const float* __restrict__ CB,
    const float* __restrict__ E2EMU,
    const unsigned char* __restrict__ FLAG,
    int nrows,
    float* __restrict__ Q,
    float* __restrict__ IDXO,
    double* __restrict__ DELTA)
{
  const int lane   = threadIdx.x & 63;
  const int gwave  = (blockIdx.x * blockDim.x + threadIdx.x) >> 6;
  const int nwaves = (gridDim.x * blockDim.x) >> 6;

  for (int base = gwave * 64; base < nrows; base += nwaves * 64) {
    int rr = base + lane;
    unsigned char f = (rr < nrows) ? FLAG[rr] : 0;
    unsigned long long mask = __ballot(f != 0);
    while (mask) {
      int bit = __ffsll((long long)mask) - 1;
      mask &= mask - 1;
      const int r = base + bit;
      const float* xr = X + (size_t)r * DD;
      const float xx = emu_sq_pairwise384(xr);   // same in all lanes

      float best = 1e30f; int bidx = 0x7fffffff;
#pragma unroll
      for (int t = 0; t < 4; ++t) {
        int k = lane * 4 + t;
        const float* ck = CB + (size_t)k * DD;
        float E = emu_dot384_np(xr, ck);
        float s = __fadd_rn(__fsub_rn(xx, __fmul_rn(2.0f, E)), E2EMU[k]);
        if (s < best || (s == best && k < bidx)) { best = s; bidx = k; }
      }
#pragma unroll
      for (int m = 1; m < 64; m <<= 1) {
        float ob = __shfl_xor(best, m);
        int   oi = __shfl_xor(bidx, m);
        if (ob < best || (ob == best && oi < bidx)) { best = ob; bidx = oi; }
      }

      const int old = (int)IDXO[r];
      if (bidx != old) {
        const float* cn = CB + (size_t)bidx * DD;
        const float* co = CB + (size_t)old * DD;
        double dl = 0.0;
        for (int d = lane; d < DD; d += 64) {
          float xv = xr[d];
          float qn = cn[d], qo = co[d];
          Q[(size_t)r * DD + d] = qn;
          double en = (double)qn - (double)xv;
          double eo = (double)qo - (double)xv;
          dl += en * en - eo * eo;
        }
#pragma unroll
        for (int m = 1; m < 64; m <<= 1) dl += __shfl_xor(dl, m);
        if (lane == 0) {
          atomicAdd(DELTA, dl);
          IDXO[r] = (float)bidx;
        }
      }
    }
  }
}

// ---------------- loss finalize ----------------
__global__ void finalize_kernel(const double* __restrict__ p0, int n0, double w0,
                                const double* __restrict__ p1, int n1, double w1,
                                const double* __restrict__ p2, int n2, double w2,
                                const double* __restrict__ delta,
                                float* __restrict__ out) {
  __shared__ double red[4];
  int tid = threadIdx.x;
  double s0 = 0.0, s1 = 0.0, s2 = 0.0;
  for (int i = tid; i < n0; i += 256) s0 += p0[i];
  for (int i = tid; i < n1; i += 256) s1 += p1[i];
  for (int i = tid; i < n2; i += 256) s2 += p2[i];
  double v = s0 * w0 + s1 * w1 + s2 * w2;
#pragma unroll
  for (int m = 1; m < 64; m <<= 1) v += __shfl_xor(v, m);
  if ((tid & 63) == 0) red[tid >> 6] = v;
  __syncthreads();
  if (tid == 0)
    out[0] = (float)(red[0] + red[1] + red[2] + red[3]
                     + delta[0] * w0 + delta[1] * w1 + delta[2] * w2);
}

extern "C" void kernel_launch(void* const* d_in, const int* in_sizes, int n_in,
                              void* d_out, int out_size, void* d_ws, size_t ws_size,
                              hipStream_t stream) {
  const float* l0  = (const float*)d_in[0];
  const float* l1  = (const float*)d_in[1];
  const float* l2  = (const float*)d_in[2];
  const float* cb0 = (const float*)d_in[3];
  const float* cb1 = (const float*)d_in[4];
  const float* cb2 = (const float*)d_in[5];

  const size_t n_q0 = (size_t)in_sizes[0];
  const size_t n_q1 = (size_t)in_sizes[1];
  const size_t n_q2 = (size_t)in_sizes[2];
  const int r0 = (int)(n_q0 / DD);   // 65536
  const int r1 = (int)(n_q1 / DD);   // 262144
  const int r2 = (int)(n_q2 / DD);   // 262144

  float* out   = (float*)d_out;
  float* q0    = out;
  float* q1    = q0 + n_q0;
  float* q2    = q1 + n_q1;
  float* lossp = q2 + n_q2;
  float* idx0  = lossp + 1;
  float* idx1  = idx0 + r0;
  float* idx2  = idx1 + r1;

  // ws layout
  float*  e2    = (float*)d_ws;                          // 3*256 f32 (3 KB)
  double* part  = (double*)((char*)d_ws + 4096);         // 9216 doubles (73728 B)
  double* delta = (double*)((char*)d_ws + 4096 + 73728); // 3 doubles
  unsigned char* flag0 = (unsigned char*)d_ws + 4096 + 73728 + 1024;
  unsigned char* flag1 = flag0 + r0;
  unsigned char* flag2 = flag1 + r1;

  const int nb0 = r0 / TM, nb1 = r1 / TM, nb2 = r2 / TM;
  double* p0 = part;
  double* p1 = p0 + nb0;
  double* p2 = p1 + nb1;

  cb_norms_kernel<<<3, 256, 0, stream>>>(cb0, cb1, cb2, e2, delta);

  vq_main<<<nb0, 256, 0, stream>>>(l0, cb0, e2 + 0 * KN, q0, idx0, flag0, p0);
  vq_main<<<nb1, 256, 0, stream>>>(l1, cb1, e2 + 1 * KN, q1, idx1, flag1, p1);
  vq_main<<<nb2, 256, 0, stream>>>(l2, cb2, e2 + 2 * KN, q2, idx2, flag2, p2);

  vq_refine<<<256, 256, 0, stream>>>(l0, cb0, e2 + 0 * KN, flag0, r0, q0, idx0, delta + 0);
  vq_refine<<<256, 256, 0, stream>>>(l1, cb1, e2 + 1 * KN, flag1, r1, q1, idx1, delta + 1);
  vq_refine<<<256, 256, 0, stream>>>(l2, cb2, e2 + 2 * KN, flag2, r2, q2, idx2, delta + 2);

  const double w0 = 0.05 / ((double)r0 * DD);
  const double w1 = 0.25 / ((double)r1 * DD);
  const double w2 = 0.60 / ((double)r2 * DD);
  finalize_kernel<<<1, 256, 0, stream>>>(p0, nb0, w0, p1, nb1, w1, p2, nb2, w2,
                                         delta, lossp);
}

// Round 6
// 15085.667 us; speedup vs baseline: 3.1845x; 3.1845x over previous
//
#include <hip/hip_runtime.h>

static constexpr int KN  = 256;   // codebook entries
static constexpr int DD  = 384;   // feature dim
static constexpr int DD4 = 96;    // DD/4
static constexpr int TM  = 64;    // rows per block
static constexpr int DK  = 32;    // D-chunk per LDS stage
#define FLAG_MARGIN 0.005f

// ======== numpy-fp32 emulation helpers (VALIDATED in round 4 — do not touch) ====

// np.sum(p*p, axis=-1), n=384: pairwise 384->(96+96)+(96+96);
// 96-block = 8 scalar accumulators, tree ((r0+r1)+(r2+r3))+((r4+r5)+(r6+r7))
__device__ __forceinline__ float emu_sq_pairwise384(const float* __restrict__ p) {
  float S[4];
#pragma unroll
  for (int blk = 0; blk < 4; ++blk) {
    const float* b = p + blk * 96;
    float r[8];
#pragma unroll
    for (int l = 0; l < 8; ++l) r[l] = __fmul_rn(b[l], b[l]);
    for (int j = 8; j < 96; j += 8) {
#pragma unroll
      for (int l = 0; l < 8; ++l) r[l] = __fadd_rn(r[l], __fmul_rn(b[j + l], b[j + l]));
    }
    float t1 = __fadd_rn(__fadd_rn(r[0], r[1]), __fadd_rn(r[2], r[3]));
    float t2 = __fadd_rn(__fadd_rn(r[4], r[5]), __fadd_rn(r[6], r[7]));
    S[blk] = __fadd_rn(t1, t2);
  }
  return __fadd_rn(__fadd_rn(S[0], S[1]), __fadd_rn(S[2], S[3]));
}

// Modern numpy einsum sum_of_products_contig_two, SSE baseline:
// 4 vector accumulators x 4 lanes, muladd = mul+add (2 roundings),
// combine (acc0+acc1)+(acc2+acc3), then SSE3 hadd tree (w0+w1)+(w2+w3).
__device__ __forceinline__ float emu_dot384_np(const float* __restrict__ x,
                                               const float* __restrict__ c) {
  float s[16];
#pragma unroll
  for (int t = 0; t < 16; ++t) s[t] = 0.f;
  for (int j = 0; j < 384; j += 16) {
#pragma unroll
    for (int t = 0; t < 16; ++t)
      s[t] = __fadd_rn(__fmul_rn(x[j + t], c[j + t]), s[t]);
  }
  float w0 = __fadd_rn(__fadd_rn(s[0], s[4]), __fadd_rn(s[8],  s[12]));
  float w1 = __fadd_rn(__fadd_rn(s[1], s[5]), __fadd_rn(s[9],  s[13]));
  float w2 = __fadd_rn(__fadd_rn(s[2], s[6]), __fadd_rn(s[10], s[14]));
  float w3 = __fadd_rn(__fadd_rn(s[3], s[7]), __fadd_rn(s[11], s[15]));
  return __fadd_rn(__fadd_rn(w0, w1), __fadd_rn(w2, w3));
}

// ---------------- codebook squared norms: exact numpy values ----------------
__global__ void cb_norms_kernel(const float* __restrict__ cb0,
                                const float* __restrict__ cb1,
                                const float* __restrict__ cb2,
                                float* __restrict__ e2,
                                double* __restrict__ delta) {
  int l = blockIdx.x;
  int k = threadIdx.x;
  const float* cb = (l == 0) ? cb0 : ((l == 1) ? cb1 : cb2);
  e2[l * KN + k] = emu_sq_pairwise384(cb + (size_t)k * DD);
  if (k == 0) delta[l] = 0.0;   // zero the loss-delta accumulators each call
}

// ---------------- phase 1: GEMM + argmin + flag (NO emu code here) ----------
// Block: 256 threads. Tile: TM=64 rows x all K=256 cols.
// Thread (rg,cg): rg=tid>>4 owns rows rg*4..rg*4+3; cg=tid&15 owns cols cg+16*c.
// NOTE: plain __launch_bounds__(256) — round 5 proved that forcing 3 waves/EU
// (84 VGPRs) spills the 64-register accumulator array (45 GB scratch traffic).
__global__ __launch_bounds__(256) void vq_main(
    const float* __restrict__ X,
    const float* __restrict__ CB,
    const float* __restrict__ E2,
    float* __restrict__ Q,
    float* __restrict__ IDXO,
    unsigned char* __restrict__ FLAG,
    double* __restrict__ PART)
{
  __shared__ float As[TM][36];
  __shared__ float Bs[KN][36];
  __shared__ int idx_s[TM];
  __shared__ double wred[4];

  const int tid = threadIdx.x;
  const int rg = tid >> 4;
  const int cg = tid & 15;
  const size_t row0 = (size_t)blockIdx.x * TM;

  const float4* X4  = reinterpret_cast<const float4*>(X);
  const float4* CB4 = reinterpret_cast<const float4*>(CB);
  float4* Q4 = reinterpret_cast<float4*>(Q);

  float acc[4][16];
#pragma unroll
  for (int j = 0; j < 4; ++j)
#pragma unroll
    for (int c = 0; c < 16; ++c) acc[j][c] = 0.f;

  for (int d0 = 0; d0 < DD; d0 += DK) {
    const int dq = d0 >> 2;
#pragma unroll
    for (int s = 0; s < 2; ++s) {
      int i = tid + s * 256;
      int r = i >> 3, f = i & 7;
      float4 v = X4[(row0 + (size_t)r) * DD4 + dq + f];
      *reinterpret_cast<float4*>(&As[r][4 * f]) = v;
    }
#pragma unroll
    for (int s = 0; s < 8; ++s) {
      int i = tid + s * 256;
      int k = i >> 3, f = i & 7;
      *reinterpret_cast<float4*>(&Bs[k][4 * f]) = CB4[(size_t)k * DD4 + dq + f];
    }
    __syncthreads();

#pragma unroll
    for (int d = 0; d < DK; d += 4) {
      float4 a0 = *reinterpret_cast<const float4*>(&As[rg * 4 + 0][d]);
      float4 a1 = *reinterpret_cast<const float4*>(&As[rg * 4 + 1][d]);
      float4 a2 = *reinterpret_cast<const float4*>(&As[rg * 4 + 2][d]);
      float4 a3 = *reinterpret_cast<const float4*>(&As[rg * 4 + 3][d]);
#pragma unroll
      for (int c = 0; c < 16; ++c) {
        float4 b = *reinterpret_cast<const float4*>(&Bs[cg + 16 * c][d]);
        acc[0][c] += a0.x * b.x + a0.y * b.y + a0.z * b.z + a0.w * b.w;
        acc[1][c] += a1.x * b.x + a1.y * b.y + a1.z * b.z + a1.w * b.w;
        acc[2][c] += a2.x * b.x + a2.y * b.y + a2.z * b.z + a2.w * b.w;
        acc[3][c] += a3.x * b.x + a3.y * b.y + a3.z * b.z + a3.w * b.w;
      }
    }
    __syncthreads();
  }

  float my_e2[16];
#pragma unroll
  for (int c = 0; c < 16; ++c) my_e2[c] = E2[cg + 16 * c];

#pragma unroll 1
  for (int j = 0; j < 4; ++j) {
    // ---- pass 1: global min (first-index tie-break) ----
    float b1 = 1e30f; int i1 = 0x7fffffff;
#pragma unroll
    for (int c = 0; c < 16; ++c) {
      int col = cg + 16 * c;
      float sc = my_e2[c] - 2.0f * acc[j][c];
      if (sc < b1 || (sc == b1 && col < i1)) { b1 = sc; i1 = col; }
    }
#pragma unroll
    for (int m = 1; m < 16; m <<= 1) {
      float ob = __shfl_xor(b1, m);
      int   oi = __shfl_xor(i1, m);
      if (ob < b1 || (ob == b1 && oi < i1)) { b1 = ob; i1 = oi; }
    }
    // ---- pass 2: runner-up value (for the flag test) ----
    float b2 = 1e30f;
#pragma unroll
    for (int c = 0; c < 16; ++c) {
      int col = cg + 16 * c;
      if (col == i1) continue;
      float sc = my_e2[c] - 2.0f * acc[j][c];
      if (sc < b2) b2 = sc;
    }
#pragma unroll
    for (int m = 1; m < 16; m <<= 1) {
      float ob = __shfl_xor(b2, m);
      if (ob < b2) b2 = ob;
    }

    if (cg == 0) {
      idx_s[rg * 4 + j] = i1;
      FLAG[row0 + (size_t)(rg * 4 + j)] = (b2 - b1 < FLAG_MARGIN) ? 1 : 0;
    }
  }
  __syncthreads();

  // ---- outputs: idx (as float), q = cb[idx], loss partial ----
  if (tid < TM) IDXO[row0 + tid] = (float)idx_s[tid];

  float lsum = 0.f;
  for (int i = tid; i < TM * DD4; i += 256) {
    int r = i / DD4;
    int c = i - r * DD4;
    int k = idx_s[r];
    float4 qv = CB4[(size_t)k * DD4 + c];
    float4 xv = X4[(row0 + (size_t)r) * DD4 + c];
    float dx = qv.x - xv.x, dy = qv.y - xv.y, dz = qv.z - xv.z, dw = qv.w - xv.w;
    lsum += dx * dx + dy * dy + dz * dz + dw * dw;
    Q4[(row0 + (size_t)r) * DD4 + c] = qv;
  }
#pragma unroll
  for (int m = 1; m < 64; m <<= 1) lsum += __shfl_xor(lsum, m);
  if ((tid & 63) == 0) wred[tid >> 6] = (double)lsum;
  __syncthreads();
  if (tid == 0) PART[blockIdx.x] = wred[0] + wred[1] + wred[2] + wred[3];
}

// ---------------- phase 2: numpy-exact refine of flagged rows ----------------
// One wave per flagged row; waves scan flag bytes 64-at-a-time via ballot.
__global__ __launch_bounds__(256) void vq_refine(
    const float* __restrict__ X,
    const float* __restrict__ CB,
    const float* __restrict__ E2EMU,
    const unsigned char* __restrict__ FLAG,
    int nrows,
    float* __restrict__ Q,
    float* __restrict__ IDXO,
    double* __restrict__ DELTA)
{
  const int lane   = threadIdx.x & 63;
  const int gwave  = (blockIdx.x * blockDim.x + threadIdx.x) >> 6;
  const int nwaves = (gridDim.x * blockDim.x) >> 6;

  for (int base = gwave * 64; base < nrows; base += nwaves * 64) {
    int rr = base + lane;
    unsigned char f = (rr < nrows) ? FLAG[rr] : 0;
    unsigned long long mask = __ballot(f != 0);
    while (mask) {
      int bit = __ffsll((long long)mask) - 1;
      mask &= mask - 1;
      const int r = base + bit;
      const float* xr = X + (size_t)r * DD;
      const float xx = emu_sq_pairwise384(xr);   // same in all lanes

      float best = 1e30f; int bidx = 0x7fffffff;
#pragma unroll
      for (int t = 0; t < 4; ++t) {
        int k = lane * 4 + t;
        const float* ck = CB + (size_t)k * DD;
        float E = emu_dot384_np(xr, ck);
        float s = __fadd_rn(__fsub_rn(xx, __fmul_rn(2.0f, E)), E2EMU[k]);
        if (s < best || (s == best && k < bidx)) { best = s; bidx = k; }
      }
#pragma unroll
      for (int m = 1; m < 64; m <<= 1) {
        float ob = __shfl_xor(best, m);
        int   oi = __shfl_xor(bidx, m);
        if (ob < best || (ob == best && oi < bidx)) { best = ob; bidx = oi; }
      }

      const int old = (int)IDXO[r];
      if (bidx != old) {
        const float* cn = CB + (size_t)bidx * DD;
        const float* co = CB + (size_t)old * DD;
        double dl = 0.0;
        for (int d = lane; d < DD; d += 64) {
          float xv = xr[d];
          float qn = cn[d], qo = co[d];
          Q[(size_t)r * DD + d] = qn;
          double en = (double)qn - (double)xv;
          double eo = (double)qo - (double)xv;
          dl += en * en - eo * eo;
        }
#pragma unroll
        for (int m = 1; m < 64; m <<= 1) dl += __shfl_xor(dl, m);
        if (lane == 0) {
          atomicAdd(DELTA, dl);
          IDXO[r] = (float)bidx;
        }
      }
    }
  }
}

// ---------------- loss finalize ----------------
__global__ void finalize_kernel(const double* __restrict__ p0, int n0, double w0,
                                const double* __restrict__ p1, int n1, double w1,
                                const double* __restrict__ p2, int n2, double w2,
                                const double* __restrict__ delta,
                                float* __restrict__ out) {
  __shared__ double red[4];
  int tid = threadIdx.x;
  double s0 = 0.0, s1 = 0.0, s2 = 0.0;
  for (int i = tid; i < n0; i += 256) s0 += p0[i];
  for (int i = tid; i < n1; i += 256) s1 += p1[i];
  for (int i = tid; i < n2; i += 256) s2 += p2[i];
  double v = s0 * w0 + s1 * w1 + s2 * w2;
#pragma unroll
  for (int m = 1; m < 64; m <<= 1) v += __shfl_xor(v, m);
  if ((tid & 63) == 0) red[tid >> 6] = v;
  __syncthreads();
  if (tid == 0)
    out[0] = (float)(red[0] + red[1] + red[2] + red[3]
                     + delta[0] * w0 + delta[1] * w1 + delta[2] * w2);
}

extern "C" void kernel_launch(void* const* d_in, const int* in_sizes, int n_in,
                              void* d_out, int out_size, void* d_ws, size_t ws_size,
                              hipStream_t stream) {
  const float* l0  = (const float*)d_in[0];
  const float* l1  = (const float*)d_in[1];
  const float* l2  = (const float*)d_in[2];
  const float* cb0 = (const float*)d_in[3];
  const float* cb1 = (const float*)d_in[4];
  const float* cb2 = (const float*)d_in[5];

  const size_t n_q0 = (size_t)in_sizes[0];
  const size_t n_q1 = (size_t)in_sizes[1];
  const size_t n_q2 = (size_t)in_sizes[2];
  const int r0 = (int)(n_q0 / DD);   // 65536
  const int r1 = (int)(n_q1 / DD);   // 262144
  const int r2 = (int)(n_q2 / DD);   // 262144

  float* out   = (float*)d_out;
  float* q0    = out;
  float* q1    = q0 + n_q0;
  float* q2    = q1 + n_q1;
  float* lossp = q2 + n_q2;
  float* idx0  = lossp + 1;
  float* idx1  = idx0 + r0;
  float* idx2  = idx1 + r1;

  // ws layout
  float*  e2    = (float*)d_ws;                          // 3*256 f32 (3 KB)
  double* part  = (double*)((char*)d_ws + 4096);         // 9216 doubles (73728 B)
  double* delta = (double*)((char*)d_ws + 4096 + 73728); // 3 doubles
  unsigned char* flag0 = (unsigned char*)d_ws + 4096 + 73728 + 1024;
  unsigned char* flag1 = flag0 + r0;
  unsigned char* flag2 = flag1 + r1;

  const int nb0 = r0 / TM, nb1 = r1 / TM, nb2 = r2 / TM;
  double* p0 = part;
  double* p1 = p0 + nb0;
  double* p2 = p1 + nb1;

  cb_norms_kernel<<<3, 256, 0, stream>>>(cb0, cb1, cb2, e2, delta);

  vq_main<<<nb0, 256, 0, stream>>>(l0, cb0, e2 + 0 * KN, q0, idx0, flag0, p0);
  vq_main<<<nb1, 256, 0, stream>>>(l1, cb1, e2 + 1 * KN, q1, idx1, flag1, p1);
  vq_main<<<nb2, 256, 0, stream>>>(l2, cb2, e2 + 2 * KN, q2, idx2, flag2, p2);

  vq_refine<<<256, 256, 0, stream>>>(l0, cb0, e2 + 0 * KN, flag0, r0, q0, idx0, delta + 0);
  vq_refine<<<256, 256, 0, stream>>>(l1, cb1, e2 + 1 * KN, flag1, r1, q1, idx1, delta + 1);
  vq_refine<<<256, 256, 0, stream>>>(l2, cb2, e2 + 2 * KN, flag2, r2, q2, idx2, delta + 2);

  const double w0 = 0.05 / ((double)r0 * DD);
  const double w1 = 0.25 / ((double)r1 * DD);
  const double w2 = 0.60 / ((double)r2 * DD);
  finalize_kernel<<<1, 256, 0, stream>>>(p0, nb0, w0, p1, nb1, w1, p2, nb2, w2,
                                         delta, lossp);
}

// Round 7
// 3128.201 us; speedup vs baseline: 15.3573x; 4.8225x over previous
//
#include <hip/hip_runtime.h>

static constexpr int KN  = 256;   // codebook entries
static constexpr int DD  = 384;   // feature dim
static constexpr int DD4 = 96;    // DD/4
static constexpr int TM  = 64;    // rows per block
static constexpr int DK  = 32;    // D-chunk per LDS stage
#define FLAG_MARGIN 0.005f

// ======== numpy-fp32 emulation helpers (VALIDATED in round 4 — do not touch) ====

// np.sum(p*p, axis=-1), n=384: pairwise 384->(96+96)+(96+96);
// 96-block = 8 scalar accumulators, tree ((r0+r1)+(r2+r3))+((r4+r5)+(r6+r7))
__device__ __forceinline__ float emu_sq_pairwise384(const float* __restrict__ p) {
  float S[4];
#pragma unroll
  for (int blk = 0; blk < 4; ++blk) {
    const float* b = p + blk * 96;
    float r[8];
#pragma unroll
    for (int l = 0; l < 8; ++l) r[l] = __fmul_rn(b[l], b[l]);
    for (int j = 8; j < 96; j += 8) {
#pragma unroll
      for (int l = 0; l < 8; ++l) r[l] = __fadd_rn(r[l], __fmul_rn(b[j + l], b[j + l]));
    }
    float t1 = __fadd_rn(__fadd_rn(r[0], r[1]), __fadd_rn(r[2], r[3]));
    float t2 = __fadd_rn(__fadd_rn(r[4], r[5]), __fadd_rn(r[6], r[7]));
    S[blk] = __fadd_rn(t1, t2);
  }
  return __fadd_rn(__fadd_rn(S[0], S[1]), __fadd_rn(S[2], S[3]));
}

// Modern numpy einsum sum_of_products_contig_two, SSE baseline:
// 4 vector accumulators x 4 lanes, muladd = mul+add (2 roundings),
// combine (acc0+acc1)+(acc2+acc3), then SSE3 hadd tree (w0+w1)+(w2+w3).
__device__ __forceinline__ float emu_dot384_np(const float* __restrict__ x,
                                               const float* __restrict__ c) {
  float s[16];
#pragma unroll
  for (int t = 0; t < 16; ++t) s[t] = 0.f;
  for (int j = 0; j < 384; j += 16) {
#pragma unroll
    for (int t = 0; t < 16; ++t)
      s[t] = __fadd_rn(__fmul_rn(x[j + t], c[j + t]), s[t]);
  }
  float w0 = __fadd_rn(__fadd_rn(s[0], s[4]), __fadd_rn(s[8],  s[12]));
  float w1 = __fadd_rn(__fadd_rn(s[1], s[5]), __fadd_rn(s[9],  s[13]));
  float w2 = __fadd_rn(__fadd_rn(s[2], s[6]), __fadd_rn(s[10], s[14]));
  float w3 = __fadd_rn(__fadd_rn(s[3], s[7]), __fadd_rn(s[11], s[15]));
  return __fadd_rn(__fadd_rn(w0, w1), __fadd_rn(w2, w3));
}

// ---------------- codebook squared norms: exact numpy values ----------------
__global__ void cb_norms_kernel(const float* __restrict__ cb0,
                                const float* __restrict__ cb1,
                                const float* __restrict__ cb2,
                                float* __restrict__ e2,
                                double* __restrict__ delta) {
  int l = blockIdx.x;
  int k = threadIdx.x;
  const float* cb = (l == 0) ? cb0 : ((l == 1) ? cb1 : cb2);
  e2[l * KN + k] = emu_sq_pairwise384(cb + (size_t)k * DD);
  if (k == 0) delta[l] = 0.0;   // zero the loss-delta accumulators each call
}

// ---------------- phase 1: GEMM + argmin + flag ----------
// Block: 256 threads. Tile: TM=64 rows x all K=256 cols.
// Thread (rg,cg): rg=tid>>4 owns rows rg*4..rg*4+3; cg=tid&15 owns cols cg+16*c.
// Round 5 lesson: no min-waves hint (84 VGPR forced -> acc spills).
// Round 6 lesson: full unroll of the d-loop hoists 160 b128 loads -> 256 VGPR
// cap -> acc spills (17 GB scratch). unroll 1 keeps live set ~150 VGPRs.
__global__ __launch_bounds__(256) void vq_main(
    const float* __restrict__ X,
    const float* __restrict__ CB,
    const float* __restrict__ E2,
    float* __restrict__ Q,
    float* __restrict__ IDXO,
    unsigned char* __restrict__ FLAG,
    double* __restrict__ PART)
{
  __shared__ float As[TM][36];
  __shared__ float Bs[KN][36];
  __shared__ int idx_s[TM];
  __shared__ double wred[4];

  const int tid = threadIdx.x;
  const int rg = tid >> 4;
  const int cg = tid & 15;
  const size_t row0 = (size_t)blockIdx.x * TM;

  const float4* X4  = reinterpret_cast<const float4*>(X);
  const float4* CB4 = reinterpret_cast<const float4*>(CB);
  float4* Q4 = reinterpret_cast<float4*>(Q);

  float acc[4][16];
#pragma unroll
  for (int j = 0; j < 4; ++j)
#pragma unroll
    for (int c = 0; c < 16; ++c) acc[j][c] = 0.f;

  for (int d0 = 0; d0 < DD; d0 += DK) {
    const int dq = d0 >> 2;
#pragma unroll
    for (int s = 0; s < 2; ++s) {
      int i = tid + s * 256;
      int r = i >> 3, f = i & 7;
      float4 v = X4[(row0 + (size_t)r) * DD4 + dq + f];
      *reinterpret_cast<float4*>(&As[r][4 * f]) = v;
    }
#pragma unroll
    for (int s = 0; s < 8; ++s) {
      int i = tid + s * 256;
      int k = i >> 3, f = i & 7;
      *reinterpret_cast<float4*>(&Bs[k][4 * f]) = CB4[(size_t)k * DD4 + dq + f];
    }
    __syncthreads();

#pragma unroll 1   // CRITICAL: full unroll spills acc[4][16] (round 6, 17 GB scratch)
    for (int d = 0; d < DK; d += 4) {
      float4 a0 = *reinterpret_cast<const float4*>(&As[rg * 4 + 0][d]);
      float4 a1 = *reinterpret_cast<const float4*>(&As[rg * 4 + 1][d]);
      float4 a2 = *reinterpret_cast<const float4*>(&As[rg * 4 + 2][d]);
      float4 a3 = *reinterpret_cast<const float4*>(&As[rg * 4 + 3][d]);
#pragma unroll
      for (int c = 0; c < 16; ++c) {
        float4 b = *reinterpret_cast<const float4*>(&Bs[cg + 16 * c][d]);
        acc[0][c] += a0.x * b.x + a0.y * b.y + a0.z * b.z + a0.w * b.w;
        acc[1][c] += a1.x * b.x + a1.y * b.y + a1.z * b.z + a1.w * b.w;
        acc[2][c] += a2.x * b.x + a2.y * b.y + a2.z * b.z + a2.w * b.w;
        acc[3][c] += a3.x * b.x + a3.y * b.y + a3.z * b.z + a3.w * b.w;
      }
    }
    __syncthreads();
  }

  float my_e2[16];
#pragma unroll
  for (int c = 0; c < 16; ++c) my_e2[c] = E2[cg + 16 * c];

#pragma unroll 1
  for (int j = 0; j < 4; ++j) {
    // ---- pass 1: global min (first-index tie-break) ----
    float b1 = 1e30f; int i1 = 0x7fffffff;
#pragma unroll
    for (int c = 0; c < 16; ++c) {
      int col = cg + 16 * c;
      float sc = my_e2[c] - 2.0f * acc[j][c];
      if (sc < b1 || (sc == b1 && col < i1)) { b1 = sc; i1 = col; }
    }
#pragma unroll
    for (int m = 1; m < 16; m <<= 1) {
      float ob = __shfl_xor(b1, m);
      int   oi = __shfl_xor(i1, m);
      if (ob < b1 || (ob == b1 && oi < i1)) { b1 = ob; i1 = oi; }
    }
    // ---- pass 2: runner-up value (for the flag test) ----
    float b2 = 1e30f;
#pragma unroll
    for (int c = 0; c < 16; ++c) {
      int col = cg + 16 * c;
      if (col == i1) continue;
      float sc = my_e2[c] - 2.0f * acc[j][c];
      if (sc < b2) b2 = sc;
    }
#pragma unroll
    for (int m = 1; m < 16; m <<= 1) {
      float ob = __shfl_xor(b2, m);
      if (ob < b2) b2 = ob;
    }

    if (cg == 0) {
      idx_s[rg * 4 + j] = i1;
      FLAG[row0 + (size_t)(rg * 4 + j)] = (b2 - b1 < FLAG_MARGIN) ? 1 : 0;
    }
  }
  __syncthreads();

  // ---- outputs: idx (as float), q = cb[idx], loss partial ----
  if (tid < TM) IDXO[row0 + tid] = (float)idx_s[tid];

  float lsum = 0.f;
  for (int i = tid; i < TM * DD4; i += 256) {
    int r = i / DD4;
    int c = i - r * DD4;
    int k = idx_s[r];
    float4 qv = CB4[(size_t)k * DD4 + c];
    float4 xv = X4[(row0 + (size_t)r) * DD4 + c];
    float dx = qv.x - xv.x, dy = qv.y - xv.y, dz = qv.z - xv.z, dw = qv.w - xv.w;
    lsum += dx * dx + dy * dy + dz * dz + dw * dw;
    Q4[(row0 + (size_t)r) * DD4 + c] = qv;
  }
#pragma unroll
  for (int m = 1; m < 64; m <<= 1) lsum += __shfl_xor(lsum, m);
  if ((tid & 63) == 0) wred[tid >> 6] = (double)lsum;
  __syncthreads();
  if (tid == 0) PART[blockIdx.x] = wred[0] + wred[1] + wred[2] + wred[3];
}

// ---------------- phase 2: numpy-exact refine of flagged rows ----------------
// One wave per flagged row; waves scan flag bytes 64-at-a-time via ballot.
__global__ __launch_bounds__(256) void vq_refine(
    const float* __restrict__ X,
    const float* __restrict__ CB,
    const float* __restrict__ E2EMU,
    const unsigned char* __restrict__ FLAG,
    int nrows,
    float* __restrict__ Q,
    float* __restrict__ IDXO,
    double* __restrict__ DELTA)
{
  const int lane   = threadIdx.x & 63;
  const int gwave  = (blockIdx.x * blockDim.x + threadIdx.x) >> 6;
  const int nwaves = (gridDim.x * blockDim.x) >> 6;

  for (int base = gwave * 64; base < nrows; base += nwaves * 64) {
    int rr = base + lane;
    unsigned char f = (rr < nrows) ? FLAG[rr] : 0;
    unsigned long long mask = __ballot(f != 0);
    while (mask) {
      int bit = __ffsll((long long)mask) - 1;
      mask &= mask - 1;
      const int r = base + bit;
      const float* xr = X + (size_t)r * DD;
      const float xx = emu_sq_pairwise384(xr);   // same in all lanes

      float best = 1e30f; int bidx = 0x7fffffff;
#pragma unroll
      for (int t = 0; t < 4; ++t) {
        int k = lane * 4 + t;
        const float* ck = CB + (size_t)k * DD;
        float E = emu_dot384_np(xr, ck);
        float s = __fadd_rn(__fsub_rn(xx, __fmul_rn(2.0f, E)), E2EMU[k]);
        if (s < best || (s == best && k < bidx)) { best = s; bidx = k; }
      }
#pragma unroll
      for (int m = 1; m < 64; m <<= 1) {
        float ob = __shfl_xor(best, m);
        int   oi = __shfl_xor(bidx, m);
        if (ob < best || (ob == best && oi < bidx)) { best = ob; bidx = oi; }
      }

      const int old = (int)IDXO[r];
      if (bidx != old) {
        const float* cn = CB + (size_t)bidx * DD;
        const float* co = CB + (size_t)old * DD;
        double dl = 0.0;
        for (int d = lane; d < DD; d += 64) {
          float xv = xr[d];
          float qn = cn[d], qo = co[d];
          Q[(size_t)r * DD + d] = qn;
          double en = (double)qn - (double)xv;
          double eo = (double)qo - (double)xv;
          dl += en * en - eo * eo;
        }
#pragma unroll
        for (int m = 1; m < 64; m <<= 1) dl += __shfl_xor(dl, m);
        if (lane == 0) {
          atomicAdd(DELTA, dl);
          IDXO[r] = (float)bidx;
        }
      }
    }
  }
}

// ---------------- loss finalize ----------------
__global__ void finalize_kernel(const double* __restrict__ p0, int n0, double w0,
                                const double* __restrict__ p1, int n1, double w1,
                                const double* __restrict__ p2, int n2, double w2,
                                const double* __restrict__ delta,
                                float* __restrict__ out) {
  __shared__ double red[4];
  int tid = threadIdx.x;
  double s0 = 0.0, s1 = 0.0, s2 = 0.0;
  for (int i = tid; i < n0; i += 256) s0 += p0[i];
  for (int i = tid; i < n1; i += 256) s1 += p1[i];
  for (int i = tid; i < n2; i += 256) s2 += p2[i];
  double v = s0 * w0 + s1 * w1 + s2 * w2;
#pragma unroll
  for (int m = 1; m < 64; m <<= 1) v += __shfl_xor(v, m);
  if ((tid & 63) == 0) red[tid >> 6] = v;
  __syncthreads();
  if (tid == 0)
    out[0] = (float)(red[0] + red[1] + red[2] + red[3]
                     + delta[0] * w0 + delta[1] * w1 + delta[2] * w2);
}

extern "C" void kernel_launch(void* const* d_in, const int* in_sizes, int n_in,
                              void* d_out, int out_size, void* d_ws, size_t ws_size,
                              hipStream_t stream) {
  const float* l0  = (const float*)d_in[0];
  const float* l1  = (const float*)d_in[1];
  const float* l2  = (const float*)d_in[2];
  const float* cb0 = (const float*)d_in[3];
  const float* cb1 = (const float*)d_in[4];
  const float* cb2 = (const float*)d_in[5];

  const size_t n_q0 = (size_t)in_sizes[0];
  const size_t n_q1 = (size_t)in_sizes[1];
  const size_t n_q2 = (size_t)in_sizes[2];
  const int r0 = (int)(n_q0 / DD);   // 65536
  const int r1 = (int)(n_q1 / DD);   // 262144
  const int r2 = (int)(n_q2 / DD);   // 262144

  float* out   = (float*)d_out;
  float* q0    = out;
  float* q1    = q0 + n_q0;
  float* q2    = q1 + n_q1;
  float* lossp = q2 + n_q2;
  float* idx0  = lossp + 1;
  float* idx1  = idx0 + r0;
  float* idx2  = idx1 + r1;

  // ws layout
  float*  e2    = (float*)d_ws;                          // 3*256 f32 (3 KB)
  double* part  = (double*)((char*)d_ws + 4096);         // 9216 doubles (73728 B)
  double* delta = (double*)((char*)d_ws + 4096 + 73728); // 3 doubles
  unsigned char* flag0 = (unsigned char*)d_ws + 4096 + 73728 + 1024;
  unsigned char* flag1 = flag0 + r0;
  unsigned char* flag2 = flag1 + r1;

  const int nb0 = r0 / TM, nb1 = r1 / TM, nb2 = r2 / TM;
  double* p0 = part;
  double* p1 = p0 + nb0;
  double* p2 = p1 + nb1;

  cb_norms_kernel<<<3, 256, 0, stream>>>(cb0, cb1, cb2, e2, delta);

  vq_main<<<nb0, 256, 0, stream>>>(l0, cb0, e2 + 0 * KN, q0, idx0, flag0, p0);
  vq_main<<<nb1, 256, 0, stream>>>(l1, cb1, e2 + 1 * KN, q1, idx1, flag1, p1);
  vq_main<<<nb2, 256, 0, stream>>>(l2, cb2, e2 + 2 * KN, q2, idx2, flag2, p2);

  vq_refine<<<256, 256, 0, stream>>>(l0, cb0, e2 + 0 * KN, flag0, r0, q0, idx0, delta + 0);
  vq_refine<<<256, 256, 0, stream>>>(l1, cb1, e2 + 1 * KN, flag1, r1, q1, idx1, delta + 1);
  vq_refine<<<256, 256, 0, stream>>>(l2, cb2, e2 + 2 * KN, flag2, r2, q2, idx2, delta + 2);

  const double w0 = 0.05 / ((double)r0 * DD);
  const double w1 = 0.25 / ((double)r1 * DD);
  const double w2 = 0.60 / ((double)r2 * DD);
  finalize_kernel<<<1, 256, 0, stream>>>(p0, nb0, w0, p1, nb1, w1, p2, nb2, w2,
                                         delta, lossp);
}

// Round 8
// 2141.280 us; speedup vs baseline: 22.4355x; 1.4609x over previous
//
#include <hip/hip_runtime.h>

static constexpr int KN  = 256;   // codebook entries
static constexpr int DD  = 384;   // feature dim
static constexpr int DD4 = 96;    // DD/4
static constexpr int TM  = 64;    // rows per block
static constexpr int DK  = 32;    // D-chunk per LDS stage
#define FLAG_MARGIN 0.005f

// ======== numpy-fp32 emulation helpers (VALIDATED in round 4 — do not touch) ====

// np.sum(p*p, axis=-1), n=384: pairwise 384->(96+96)+(96+96);
// 96-block = 8 scalar accumulators, tree ((r0+r1)+(r2+r3))+((r4+r5)+(r6+r7))
__device__ __forceinline__ float emu_sq_pairwise384(const float* __restrict__ p) {
  float S[4];
#pragma unroll
  for (int blk = 0; blk < 4; ++blk) {
    const float* b = p + blk * 96;
    float r[8];
#pragma unroll
    for (int l = 0; l < 8; ++l) r[l] = __fmul_rn(b[l], b[l]);
    for (int j = 8; j < 96; j += 8) {
#pragma unroll
      for (int l = 0; l < 8; ++l) r[l] = __fadd_rn(r[l], __fmul_rn(b[j + l], b[j + l]));
    }
    float t1 = __fadd_rn(__fadd_rn(r[0], r[1]), __fadd_rn(r[2], r[3]));
    float t2 = __fadd_rn(__fadd_rn(r[4], r[5]), __fadd_rn(r[6], r[7]));
    S[blk] = __fadd_rn(t1, t2);
  }
  return __fadd_rn(__fadd_rn(S[0], S[1]), __fadd_rn(S[2], S[3]));
}

// Modern numpy einsum sum_of_products_contig_two, SSE baseline:
// 4 vector accumulators x 4 lanes, muladd = mul+add (2 roundings),
// combine (acc0+acc1)+(acc2+acc3), then SSE3 hadd tree (w0+w1)+(w2+w3).
__device__ __forceinline__ float emu_dot384_np(const float* __restrict__ x,
                                               const float* __restrict__ c) {
  float s[16];
#pragma unroll
  for (int t = 0; t < 16; ++t) s[t] = 0.f;
  for (int j = 0; j < 384; j += 16) {
#pragma unroll
    for (int t = 0; t < 16; ++t)
      s[t] = __fadd_rn(__fmul_rn(x[j + t], c[j + t]), s[t]);
  }
  float w0 = __fadd_rn(__fadd_rn(s[0], s[4]), __fadd_rn(s[8],  s[12]));
  float w1 = __fadd_rn(__fadd_rn(s[1], s[5]), __fadd_rn(s[9],  s[13]));
  float w2 = __fadd_rn(__fadd_rn(s[2], s[6]), __fadd_rn(s[10], s[14]));
  float w3 = __fadd_rn(__fadd_rn(s[3], s[7]), __fadd_rn(s[11], s[15]));
  return __fadd_rn(__fadd_rn(w0, w1), __fadd_rn(w2, w3));
}

// ---------------- codebook squared norms: exact numpy values ----------------
__global__ void cb_norms_kernel(const float* __restrict__ cb0,
                                const float* __restrict__ cb1,
                                const float* __restrict__ cb2,
                                float* __restrict__ e2,
                                double* __restrict__ delta) {
  int l = blockIdx.x;
  int k = threadIdx.x;
  const float* cb = (l == 0) ? cb0 : ((l == 1) ? cb1 : cb2);
  e2[l * KN + k] = emu_sq_pairwise384(cb + (size_t)k * DD);
  if (k == 0) delta[l] = 0.0;   // zero the loss-delta accumulators each call
}

// ---------------- phase 1: GEMM + argmin + flag ----------
// Block: 256 threads. Tile: TM=64 rows x all K=256 cols.
// Thread (rg,cg): rg=tid>>4 owns rows rg*4..rg*4+3; cg=tid&15 owns cols cg+16*c.
// Round 5 lesson: no min-waves hint (84 VGPR forced -> acc spills).
// Round 6 lesson: full unroll of the d-loop hoists 160 b128 loads -> spills.
// Round 7 lesson (rule #20): `#pragma unroll 1` on the argmin j-loop made
// acc[j][c] RUNTIME-indexed -> whole acc array demoted to scratch (VGPR=76,
// 3.9 GB scratch writes). ALL acc accesses must be compile-time-indexed.
__global__ __launch_bounds__(256) void vq_main(
    const float* __restrict__ X,
    const float* __restrict__ CB,
    const float* __restrict__ E2,
    float* __restrict__ Q,
    float* __restrict__ IDXO,
    unsigned char* __restrict__ FLAG,
    double* __restrict__ PART)
{
  __shared__ float As[TM][36];
  __shared__ float Bs[KN][36];
  __shared__ int idx_s[TM];
  __shared__ double wred[4];

  const int tid = threadIdx.x;
  const int rg = tid >> 4;
  const int cg = tid & 15;
  const size_t row0 = (size_t)blockIdx.x * TM;

  const float4* X4  = reinterpret_cast<const float4*>(X);
  const float4* CB4 = reinterpret_cast<const float4*>(CB);
  float4* Q4 = reinterpret_cast<float4*>(Q);

  float acc[4][16];
#pragma unroll
  for (int j = 0; j < 4; ++j)
#pragma unroll
    for (int c = 0; c < 16; ++c) acc[j][c] = 0.f;

  for (int d0 = 0; d0 < DD; d0 += DK) {
    const int dq = d0 >> 2;
#pragma unroll
    for (int s = 0; s < 2; ++s) {
      int i = tid + s * 256;
      int r = i >> 3, f = i & 7;
      float4 v = X4[(row0 + (size_t)r) * DD4 + dq + f];
      *reinterpret_cast<float4*>(&As[r][4 * f]) = v;
    }
#pragma unroll
    for (int s = 0; s < 8; ++s) {
      int i = tid + s * 256;
      int k = i >> 3, f = i & 7;
      *reinterpret_cast<float4*>(&Bs[k][4 * f]) = CB4[(size_t)k * DD4 + dq + f];
    }
    __syncthreads();

#pragma unroll 1   // full unroll spills (round 6); one iteration has enough ILP
    for (int d = 0; d < DK; d += 4) {
      float4 a0 = *reinterpret_cast<const float4*>(&As[rg * 4 + 0][d]);
      float4 a1 = *reinterpret_cast<const float4*>(&As[rg * 4 + 1][d]);
      float4 a2 = *reinterpret_cast<const float4*>(&As[rg * 4 + 2][d]);
      float4 a3 = *reinterpret_cast<const float4*>(&As[rg * 4 + 3][d]);
#pragma unroll
      for (int c = 0; c < 16; ++c) {
        float4 b = *reinterpret_cast<const float4*>(&Bs[cg + 16 * c][d]);
        acc[0][c] += a0.x * b.x + a0.y * b.y + a0.z * b.z + a0.w * b.w;
        acc[1][c] += a1.x * b.x + a1.y * b.y + a1.z * b.z + a1.w * b.w;
        acc[2][c] += a2.x * b.x + a2.y * b.y + a2.z * b.z + a2.w * b.w;
        acc[3][c] += a3.x * b.x + a3.y * b.y + a3.z * b.z + a3.w * b.w;
      }
    }
    __syncthreads();
  }

  float my_e2[16];
#pragma unroll
  for (int c = 0; c < 16; ++c) my_e2[c] = E2[cg + 16 * c];

  // FULLY UNROLLED j-loop: every acc[j][c] access compile-time-indexed (rule #20)
#pragma unroll
  for (int j = 0; j < 4; ++j) {
    // ---- pass 1: global min (first-index tie-break) ----
    float b1 = 1e30f; int i1 = 0x7fffffff;
#pragma unroll
    for (int c = 0; c < 16; ++c) {
      int col = cg + 16 * c;
      float sc = my_e2[c] - 2.0f * acc[j][c];
      if (sc < b1 || (sc == b1 && col < i1)) { b1 = sc; i1 = col; }
    }
#pragma unroll
    for (int m = 1; m < 16; m <<= 1) {
      float ob = __shfl_xor(b1, m);
      int   oi = __shfl_xor(i1, m);
      if (ob < b1 || (ob == b1 && oi < i1)) { b1 = ob; i1 = oi; }
    }
    // ---- pass 2: runner-up value (for the flag test) ----
    float b2 = 1e30f;
#pragma unroll
    for (int c = 0; c < 16; ++c) {
      int col = cg + 16 * c;
      if (col == i1) continue;
      float sc = my_e2[c] - 2.0f * acc[j][c];
      if (sc < b2) b2 = sc;
    }
#pragma unroll
    for (int m = 1; m < 16; m <<= 1) {
      float ob = __shfl_xor(b2, m);
      if (ob < b2) b2 = ob;
    }

    if (cg == 0) {
      idx_s[rg * 4 + j] = i1;
      FLAG[row0 + (size_t)(rg * 4 + j)] = (b2 - b1 < FLAG_MARGIN) ? 1 : 0;
    }
  }
  __syncthreads();

  // ---- outputs: idx (as float), q = cb[idx], loss partial ----
  if (tid < TM) IDXO[row0 + tid] = (float)idx_s[tid];

  float lsum = 0.f;
  for (int i = tid; i < TM * DD4; i += 256) {
    int r = i / DD4;
    int c = i - r * DD4;
    int k = idx_s[r];
    float4 qv = CB4[(size_t)k * DD4 + c];
    float4 xv = X4[(row0 + (size_t)r) * DD4 + c];
    float dx = qv.x - xv.x, dy = qv.y - xv.y, dz = qv.z - xv.z, dw = qv.w - xv.w;
    lsum += dx * dx + dy * dy + dz * dz + dw * dw;
    Q4[(row0 + (size_t)r) * DD4 + c] = qv;
  }
#pragma unroll
  for (int m = 1; m < 64; m <<= 1) lsum += __shfl_xor(lsum, m);
  if ((tid & 63) == 0) wred[tid >> 6] = (double)lsum;
  __syncthreads();
  if (tid == 0) PART[blockIdx.x] = wred[0] + wred[1] + wred[2] + wred[3];
}

// ---------------- phase 2: numpy-exact refine of flagged rows ----------------
// One wave per flagged row; waves scan flag bytes 64-at-a-time via ballot.
__global__ __launch_bounds__(256) void vq_refine(
    const float* __restrict__ X,
    const float* __restrict__ CB,
    const float* __restrict__ E2EMU,
    const unsigned char* __restrict__ FLAG,
    int nrows,
    float* __restrict__ Q,
    float* __restrict__ IDXO,
    double* __restrict__ DELTA)
{
  const int lane   = threadIdx.x & 63;
  const int gwave  = (blockIdx.x * blockDim.x + threadIdx.x) >> 6;
  const int nwaves = (gridDim.x * blockDim.x) >> 6;

  for (int base = gwave * 64; base < nrows; base += nwaves * 64) {
    int rr = base + lane;
    unsigned char f = (rr < nrows) ? FLAG[rr] : 0;
    unsigned long long mask = __ballot(f != 0);
    while (mask) {
      int bit = __ffsll((long long)mask) - 1;
      mask &= mask - 1;
      const int r = base + bit;
      const float* xr = X + (size_t)r * DD;
      const float xx = emu_sq_pairwise384(xr);   // same in all lanes

      float best = 1e30f; int bidx = 0x7fffffff;
#pragma unroll
      for (int t = 0; t < 4; ++t) {
        int k = lane * 4 + t;
        const float* ck = CB + (size_t)k * DD;
        float E = emu_dot384_np(xr, ck);
        float s = __fadd_rn(__fsub_rn(xx, __fmul_rn(2.0f, E)), E2EMU[k]);
        if (s < best || (s == best && k < bidx)) { best = s; bidx = k; }
      }
#pragma unroll
      for (int m = 1; m < 64; m <<= 1) {
        float ob = __shfl_xor(best, m);
        int   oi = __shfl_xor(bidx, m);
        if (ob < best || (ob == best && oi < bidx)) { best = ob; bidx = oi; }
      }

      const int old = (int)IDXO[r];
      if (bidx != old) {
        const float* cn = CB + (size_t)bidx * DD;
        const float* co = CB + (size_t)old * DD;
        double dl = 0.0;
        for (int d = lane; d < DD; d += 64) {
          float xv = xr[d];
          float qn = cn[d], qo = co[d];
          Q[(size_t)r * DD + d] = qn;
          double en = (double)qn - (double)xv;
          double eo = (double)qo - (double)xv;
          dl += en * en - eo * eo;
        }
#pragma unroll
        for (int m = 1; m < 64; m <<= 1) dl += __shfl_xor(dl, m);
        if (lane == 0) {
          atomicAdd(DELTA, dl);
          IDXO[r] = (float)bidx;
        }
      }
    }
  }
}

// ---------------- loss finalize ----------------
__global__ void finalize_kernel(const double* __restrict__ p0, int n0, double w0,
                                const double* __restrict__ p1, int n1, double w1,
                                const double* __restrict__ p2, int n2, double w2,
                                const double* __restrict__ delta,
                                float* __restrict__ out) {
  __shared__ double red[4];
  int tid = threadIdx.x;
  double s0 = 0.0, s1 = 0.0, s2 = 0.0;
  for (int i = tid; i < n0; i += 256) s0 += p0[i];
  for (int i = tid; i < n1; i += 256) s1 += p1[i];
  for (int i = tid; i < n2; i += 256) s2 += p2[i];
  double v = s0 * w0 + s1 * w1 + s2 * w2;
#pragma unroll
  for (int m = 1; m < 64; m <<= 1) v += __shfl_xor(v, m);
  if ((tid & 63) == 0) red[tid >> 6] = v;
  __syncthreads();
  if (tid == 0)
    out[0] = (float)(red[0] + red[1] + red[2] + red[3]
                     + delta[0] * w0 + delta[1] * w1 + delta[2] * w2);
}

extern "C" void kernel_launch(void* const* d_in, const int* in_sizes, int n_in,
                              void* d_out, int out_size, void* d_ws, size_t ws_size,
                              hipStream_t stream) {
  const float* l0  = (const float*)d_in[0];
  const float* l1  = (const float*)d_in[1];
  const float* l2  = (const float*)d_in[2];
  const float* cb0 = (const float*)d_in[3];
  const float* cb1 = (const float*)d_in[4];
  const float* cb2 = (const float*)d_in[5];

  const size_t n_q0 = (size_t)in_sizes[0];
  const size_t n_q1 = (size_t)in_sizes[1];
  const size_t n_q2 = (size_t)in_sizes[2];
  const int r0 = (int)(n_q0 / DD);   // 65536
  const int r1 = (int)(n_q1 / DD);   // 262144
  const int r2 = (int)(n_q2 / DD);   // 262144

  float* out   = (float*)d_out;
  float* q0    = out;
  float* q1    = q0 + n_q0;
  float* q2    = q1 + n_q1;
  float* lossp = q2 + n_q2;
  float* idx0  = lossp + 1;
  float* idx1  = idx0 + r0;
  float* idx2  = idx1 + r1;

  // ws layout
  float*  e2    = (float*)d_ws;                          // 3*256 f32 (3 KB)
  double* part  = (double*)((char*)d_ws + 4096);         // 9216 doubles (73728 B)
  double* delta = (double*)((char*)d_ws + 4096 + 73728); // 3 doubles
  unsigned char* flag0 = (unsigned char*)d_ws + 4096 + 73728 + 1024;
  unsigned char* flag1 = flag0 + r0;
  unsigned char* flag2 = flag1 + r1;

  const int nb0 = r0 / TM, nb1 = r1 / TM, nb2 = r2 / TM;
  double* p0 = part;
  double* p1 = p0 + nb0;
  double* p2 = p1 + nb1;

  cb_norms_kernel<<<3, 256, 0, stream>>>(cb0, cb1, cb2, e2, delta);

  vq_main<<<nb0, 256, 0, stream>>>(l0, cb0, e2 + 0 * KN, q0, idx0, flag0, p0);
  vq_main<<<nb1, 256, 0, stream>>>(l1, cb1, e2 + 1 * KN, q1, idx1, flag1, p1);
  vq_main<<<nb2, 256, 0, stream>>>(l2, cb2, e2 + 2 * KN, q2, idx2, flag2, p2);

  vq_refine<<<256, 256, 0, stream>>>(l0, cb0, e2 + 0 * KN, flag0, r0, q0, idx0, delta + 0);
  vq_refine<<<256, 256, 0, stream>>>(l1, cb1, e2 + 1 * KN, flag1, r1, q1, idx1, delta + 1);
  vq_refine<<<256, 256, 0, stream>>>(l2, cb2, e2 + 2 * KN, flag2, r2, q2, idx2, delta + 2);

  const double w0 = 0.05 / ((double)r0 * DD);
  const double w1 = 0.25 / ((double)r1 * DD);
  const double w2 = 0.60 / ((double)r2 * DD);
  finalize_kernel<<<1, 256, 0, stream>>>(p0, nb0, w0, p1, nb1, w1, p2, nb2, w2,
                                         delta, lossp);
}

// Round 9
// 1469.017 us; speedup vs baseline: 32.7026x; 1.4576x over previous
//
#include <hip/hip_runtime.h>

static constexpr int KN  = 256;   // codebook entries
static constexpr int DD  = 384;   // feature dim
static constexpr int DD4 = 96;    // DD/4
static constexpr int TM  = 128;   // rows per block (MFMA version)
#define FLAG_MARGIN 0.005f

typedef __attribute__((ext_vector_type(8)))  short bf16x8;   // 8 bf16 = 4 VGPR
typedef __attribute__((ext_vector_type(16))) float f32x16;   // MFMA 32x32 acc
typedef __attribute__((ext_vector_type(4)))  short short4v;

__device__ __forceinline__ unsigned short f2bf_rne(float x) {
  unsigned u = __float_as_uint(x);
  return (unsigned short)((u + 0x7fffu + ((u >> 16) & 1u)) >> 16);
}

// ======== numpy-fp32 emulation helpers (VALIDATED round 4 — do not touch) ====
__device__ __forceinline__ float emu_sq_pairwise384(const float* __restrict__ p) {
  float S[4];
#pragma unroll
  for (int blk = 0; blk < 4; ++blk) {
    const float* b = p + blk * 96;
    float r[8];
#pragma unroll
    for (int l = 0; l < 8; ++l) r[l] = __fmul_rn(b[l], b[l]);
    for (int j = 8; j < 96; j += 8) {
#pragma unroll
      for (int l = 0; l < 8; ++l) r[l] = __fadd_rn(r[l], __fmul_rn(b[j + l], b[j + l]));
    }
    float t1 = __fadd_rn(__fadd_rn(r[0], r[1]), __fadd_rn(r[2], r[3]));
    float t2 = __fadd_rn(__fadd_rn(r[4], r[5]), __fadd_rn(r[6], r[7]));
    S[blk] = __fadd_rn(t1, t2);
  }
  return __fadd_rn(__fadd_rn(S[0], S[1]), __fadd_rn(S[2], S[3]));
}

__device__ __forceinline__ float emu_dot384_np(const float* __restrict__ x,
                                               const float* __restrict__ c) {
  float s[16];
#pragma unroll
  for (int t = 0; t < 16; ++t) s[t] = 0.f;
  for (int j = 0; j < 384; j += 16) {
#pragma unroll
    for (int t = 0; t < 16; ++t)
      s[t] = __fadd_rn(__fmul_rn(x[j + t], c[j + t]), s[t]);
  }
  float w0 = __fadd_rn(__fadd_rn(s[0], s[4]), __fadd_rn(s[8],  s[12]));
  float w1 = __fadd_rn(__fadd_rn(s[1], s[5]), __fadd_rn(s[9],  s[13]));
  float w2 = __fadd_rn(__fadd_rn(s[2], s[6]), __fadd_rn(s[10], s[14]));
  float w3 = __fadd_rn(__fadd_rn(s[3], s[7]), __fadd_rn(s[11], s[15]));
  return __fadd_rn(__fadd_rn(w0, w1), __fadd_rn(w2, w3));
}

// ---------------- codebook squared norms: exact numpy values ----------------
__global__ void cb_norms_kernel(const float* __restrict__ cb0,
                                const float* __restrict__ cb1,
                                const float* __restrict__ cb2,
                                float* __restrict__ e2,
                                double* __restrict__ delta) {
  int l = blockIdx.x;
  int k = threadIdx.x;
  const float* cb = (l == 0) ? cb0 : ((l == 1) ? cb1 : cb2);
  e2[l * KN + k] = emu_sq_pairwise384(cb + (size_t)k * DD);
  if (k == 0) delta[l] = 0.0;
}

// ---------------- codebook bf16-split, fragment-ordered --------------------
// frag layout: [chunk(12)][tile(8)][ks(2)][hl(2)] blocks of 1024B; within a
// block lane=(entry&31)+32*((k>>3)&1) holds 8 bf16 (16B) = its B-fragment.
__global__ __launch_bounds__(256) void cb_split_kernel(const float* __restrict__ cb,
                                                       short* __restrict__ frag) {
  int gid = blockIdx.x * 256 + threadIdx.x;       // 12288 = 256 entries * 48 groups
  int e = gid / 48;
  int g = gid - e * 48;                           // 8-k group
  const float4* s4 = reinterpret_cast<const float4*>(cb) + (size_t)e * 96 + g * 2;
  float4 v0 = s4[0], v1 = s4[1];
  float xs[8] = {v0.x, v0.y, v0.z, v0.w, v1.x, v1.y, v1.z, v1.w};
  short h[8], l[8];
#pragma unroll
  for (int i = 0; i < 8; ++i) {
    h[i] = (short)f2bf_rne(xs[i]);
    float hf = __uint_as_float((unsigned)(unsigned short)h[i] << 16);
    l[i] = (short)f2bf_rne(xs[i] - hf);
  }
  int c = g >> 2, rem = g & 3, ks = rem >> 1, hs = rem & 1;
  int t = e >> 5, lane = (e & 31) + (hs << 5);
  size_t blk = (((size_t)(c * 8 + t) * 2 + ks) * 2);   // h block index (1024B units)
  short* dh = frag + blk * 512 + lane * 8;
  short* dl = dh + 512;
  *reinterpret_cast<bf16x8*>(dh) = *reinterpret_cast<const bf16x8*>(h);
  *reinterpret_cast<bf16x8*>(dl) = *reinterpret_cast<const bf16x8*>(l);
}

// ---------------- phase 1: MFMA GEMM + argmin + flag ----------------
// 4 waves: wave (wr,wc) owns rows wr*64..+63, cols wc*128..+127 as 2x4 32x32
// tiles. dot = xh*ch + xh*cl + xl*ch (bf16 split, err ~1.5e-4 << FLAG_MARGIN).
__global__ __launch_bounds__(256) void vq_main(
    const float* __restrict__ X,
    const float* __restrict__ CBF32,
    const short* __restrict__ CBFRAG,
    const float* __restrict__ E2,
    float* __restrict__ Q,
    float* __restrict__ IDXO,
    unsigned char* __restrict__ FLAG,
    double* __restrict__ PART)
{
  __shared__ short cb_lds[16384];   // 32KB: [t(8)][ks(2)][hl(2)] 1KB frag blocks
  __shared__ short x_lds[8192];     // 16KB: [rt(4)][ks(2)][hl(2)] 1KB frag blocks
  __shared__ int idx_s[TM];
  __shared__ double wred[4];

  const int tid  = threadIdx.x;
  const int wid  = tid >> 6, lane = tid & 63;
  const int lr   = lane & 31, hi = lane >> 5;
  const int wr   = wid >> 1, wc = wid & 1;
  const size_t row0 = (size_t)blockIdx.x * TM;
  const float4* X4 = reinterpret_cast<const float4*>(X);

  f32x16 acc0[4], acc1[4];
  {
    f32x16 z;
#pragma unroll
    for (int i = 0; i < 16; ++i) z[i] = 0.f;
#pragma unroll
    for (int ct = 0; ct < 4; ++ct) { acc0[ct] = z; acc1[ct] = z; }
  }

#pragma unroll 1
  for (int c = 0; c < 12; ++c) {
    // stage CB chunk: pure linear 32KB copy (fragment-ordered in ws)
    const float4* src = reinterpret_cast<const float4*>(CBFRAG) + (size_t)c * 2048 + tid;
    float4* cdst = reinterpret_cast<float4*>(cb_lds);
#pragma unroll
    for (int s = 0; s < 8; ++s) cdst[tid + s * 256] = src[s * 256];
    // stage X chunk: 128 rows x 32 k fp32 -> bf16 h/l, fragment-ordered
#pragma unroll
    for (int i = 0; i < 4; ++i) {
      int idx = tid + i * 256;
      int r = idx >> 3, k4 = idx & 7;
      float4 v = X4[(row0 + (size_t)r) * DD4 + c * 8 + k4];
      float xs[4] = {v.x, v.y, v.z, v.w};
      short h[4], l[4];
#pragma unroll
      for (int e = 0; e < 4; ++e) {
        h[e] = (short)f2bf_rne(xs[e]);
        float hf = __uint_as_float((unsigned)(unsigned short)h[e] << 16);
        l[e] = (short)f2bf_rne(xs[e] - hf);
      }
      int rt = r >> 5, ks = k4 >> 2, hs = (k4 >> 1) & 1, lx = (r & 31) + (hs << 5);
      int base = ((rt * 2 + ks) * 2) * 512 + lx * 8 + (k4 & 1) * 4;
      *reinterpret_cast<short4v*>(&x_lds[base])       = *reinterpret_cast<short4v*>(h);
      *reinterpret_cast<short4v*>(&x_lds[base + 512]) = *reinterpret_cast<short4v*>(l);
    }
    __syncthreads();

#pragma unroll 1
    for (int ks = 0; ks < 2; ++ks) {
      const bf16x8* xb = reinterpret_cast<const bf16x8*>(x_lds);
      const bf16x8* bb = reinterpret_cast<const bf16x8*>(cb_lds);
      bf16x8 ah0 = xb[(((wr * 2 + 0) * 2 + ks) * 2 + 0) * 64 + lane];
      bf16x8 al0 = xb[(((wr * 2 + 0) * 2 + ks) * 2 + 1) * 64 + lane];
      bf16x8 ah1 = xb[(((wr * 2 + 1) * 2 + ks) * 2 + 0) * 64 + lane];
      bf16x8 al1 = xb[(((wr * 2 + 1) * 2 + ks) * 2 + 1) * 64 + lane];
#pragma unroll
      for (int ct = 0; ct < 4; ++ct) {
        int t = wc * 4 + ct;
        bf16x8 bh = bb[((t * 2 + ks) * 2 + 0) * 64 + lane];
        bf16x8 bl = bb[((t * 2 + ks) * 2 + 1) * 64 + lane];
        acc0[ct] = __builtin_amdgcn_mfma_f32_32x32x16_bf16(ah0, bh, acc0[ct], 0, 0, 0);
        acc0[ct] = __builtin_amdgcn_mfma_f32_32x32x16_bf16(ah0, bl, acc0[ct], 0, 0, 0);
        acc0[ct] = __builtin_amdgcn_mfma_f32_32x32x16_bf16(al0, bh, acc0[ct], 0, 0, 0);
        acc1[ct] = __builtin_amdgcn_mfma_f32_32x32x16_bf16(ah1, bh, acc1[ct], 0, 0, 0);
        acc1[ct] = __builtin_amdgcn_mfma_f32_32x32x16_bf16(ah1, bl, acc1[ct], 0, 0, 0);
        acc1[ct] = __builtin_amdgcn_mfma_f32_32x32x16_bf16(al1, bh, acc1[ct], 0, 0, 0);
      }
    }
    __syncthreads();
  }

  // ---- argmin epilogue: D layout col=lane&31, row=(v&3)+8*(v>>2)+4*hi ----
  float e2v[4];
#pragma unroll
  for (int ct = 0; ct < 4; ++ct) e2v[ct] = E2[wc * 128 + ct * 32 + lr];

#define EPILOGUE(ACC, RT)                                                     \
  {                                                                           \
    _Pragma("unroll")                                                         \
    for (int v = 0; v < 16; ++v) {                                            \
      int rloc = (v & 3) + 8 * (v >> 2) + 4 * hi;                             \
      int row = wr * 64 + (RT) * 32 + rloc;                                   \
      float b1 = 1e30f; int i1 = 0x7fffffff;                                  \
      _Pragma("unroll")                                                       \
      for (int ct = 0; ct < 4; ++ct) {                                        \
        float sc = e2v[ct] - 2.0f * ACC[ct][v];                               \
        int col = wc * 128 + ct * 32 + lr;                                    \
        if (sc < b1) { b1 = sc; i1 = col; }                                   \
      }                                                                       \
      _Pragma("unroll")                                                       \
      for (int m = 1; m < 32; m <<= 1) {                                      \
        float ob = __shfl_xor(b1, m);                                         \
        int   oi = __shfl_xor(i1, m);                                         \
        if (ob < b1 || (ob == b1 && oi < i1)) { b1 = ob; i1 = oi; }           \
      }                                                                       \
      float b2 = 1e30f;                                                       \
      _Pragma("unroll")                                                       \
      for (int ct = 0; ct < 4; ++ct) {                                        \
        float sc = e2v[ct] - 2.0f * ACC[ct][v];                               \
        int col = wc * 128 + ct * 32 + lr;                                    \
        if (col != i1 && sc < b2) b2 = sc;                                    \
      }                                                                       \
      _Pragma("unroll")                                                       \
      for (int m = 1; m < 32; m <<= 1) {                                      \
        float ob = __shfl_xor(b2, m);                                         \
        if (ob < b2) b2 = ob;                                                 \
      }                                                                       \
      if (lr == 0 && wc == 0) {                                               \
        idx_s[row] = i1;                                                      \
      }                                                                       \
      if (lr == 1 && wc == 0) { /* placeholder keeps lanes symmetric */ }     \
      if (lr == 0 && wc == 1) {                                               \
        /* col-half 1 result merged below via LDS-free trick: */              \
      }                                                                       \
    }                                                                         \
  }

  // NOTE: two col-half waves each have a partial argmin over 128 cols.
  // Merge via LDS: each writes its (b1,i1,b2) then wave 0-half merges.
  // Simpler correct scheme: both halves write candidate triplets to LDS.
  __shared__ float cand_b1[2][TM];
  __shared__ int   cand_i1[2][TM];
  __shared__ float cand_b2[2][TM];
#undef EPILOGUE

#pragma unroll
  for (int rt = 0; rt < 2; ++rt) {
#pragma unroll
    for (int v = 0; v < 16; ++v) {
      int rloc = (v & 3) + 8 * (v >> 2) + 4 * hi;
      int row = wr * 64 + rt * 32 + rloc;
      float b1 = 1e30f; int i1 = 0x7fffffff;
#pragma unroll
      for (int ct = 0; ct < 4; ++ct) {
        float sc = e2v[ct] - 2.0f * (rt == 0 ? acc0[ct][v] : acc1[ct][v]);
        int col = wc * 128 + ct * 32 + lr;
        if (sc < b1) { b1 = sc; i1 = col; }
      }
#pragma unroll
      for (int m = 1; m < 32; m <<= 1) {
        float ob = __shfl_xor(b1, m);
        int   oi = __shfl_xor(i1, m);
        if (ob < b1 || (ob == b1 && oi < i1)) { b1 = ob; i1 = oi; }
      }
      float b2 = 1e30f;
#pragma unroll
      for (int ct = 0; ct < 4; ++ct) {
        float sc = e2v[ct] - 2.0f * (rt == 0 ? acc0[ct][v] : acc1[ct][v]);
        int col = wc * 128 + ct * 32 + lr;
        if (col != i1 && sc < b2) b2 = sc;
      }
#pragma unroll
      for (int m = 1; m < 32; m <<= 1) {
        float ob = __shfl_xor(b2, m);
        if (ob < b2) b2 = ob;
      }
      if (lr == 0) {
        cand_b1[wc][row] = b1; cand_i1[wc][row] = i1; cand_b2[wc][row] = b2;
      }
    }
  }
  __syncthreads();

  // merge halves + write idx/flag (first 128 threads, one per row)
  if (tid < TM) {
    float a1 = cand_b1[0][tid], a2 = cand_b2[0][tid];
    int   ai = cand_i1[0][tid];
    float c1 = cand_b1[1][tid], c2 = cand_b2[1][tid];
    int   ci = cand_i1[1][tid];
    float b1; int i1; float b2;
    if (c1 < a1 || (c1 == a1 && ci < ai)) {
      b1 = c1; i1 = ci; b2 = (a1 < c2) ? a1 : c2;
    } else {
      b1 = a1; i1 = ai; b2 = (c1 < a2) ? c1 : a2;
    }
    idx_s[tid] = i1;
    IDXO[row0 + tid] = (float)i1;
    FLAG[row0 + tid] = (b2 - b1 < FLAG_MARGIN) ? 1 : 0;
  }
  __syncthreads();

  // ---- outputs: q = cb[idx] (fp32 gather), loss partial ----
  const float4* CB4 = reinterpret_cast<const float4*>(CBF32);
  float4* Q4 = reinterpret_cast<float4*>(Q);
  float lsum = 0.f;
  for (int i = tid; i < TM * DD4; i += 256) {
    int r = i / DD4;
    int cc = i - r * DD4;
    int k = idx_s[r];
    float4 qv = CB4[(size_t)k * DD4 + cc];
    float4 xv = X4[(row0 + (size_t)r) * DD4 + cc];
    float dx = qv.x - xv.x, dy = qv.y - xv.y, dz = qv.z - xv.z, dw = qv.w - xv.w;
    lsum += dx * dx + dy * dy + dz * dz + dw * dw;
    Q4[(row0 + (size_t)r) * DD4 + cc] = qv;
  }
#pragma unroll
  for (int m = 1; m < 64; m <<= 1) lsum += __shfl_xor(lsum, m);
  if ((tid & 63) == 0) wred[tid >> 6] = (double)lsum;
  __syncthreads();
  if (tid == 0) PART[blockIdx.x] = wred[0] + wred[1] + wred[2] + wred[3];
}

// ---------------- phase 2: numpy-exact refine of flagged rows ----------------
__global__ __launch_bounds__(256) void vq_refine(
    const float* __restrict__ X,
    const float* __restrict__ CB,
    const float* __restrict__ E2EMU,
    const unsigned char* __restrict__ FLAG,
    int nrows,
    float* __restrict__ Q,
    float* __restrict__ IDXO,
    double* __restrict__ DELTA)
{
  const int lane   = threadIdx.x & 63;
  const int gwave  = (blockIdx.x * blockDim.x + threadIdx.x) >> 6;
  const int nwaves = (gridDim.x * blockDim.x) >> 6;

  for (int base = gwave * 64; base < nrows; base += nwaves * 64) {
    int rr = base + lane;
    unsigned char f = (rr < nrows) ? FLAG[rr] : 0;
    unsigned long long mask = __ballot(f != 0);
    while (mask) {
      int bit = __ffsll((long long)mask) - 1;
      mask &= mask - 1;
      const int r = base + bit;
      const float* xr = X + (size_t)r * DD;
      const float xx = emu_sq_pairwise384(xr);

      float best = 1e30f; int bidx = 0x7fffffff;
#pragma unroll
      for (int t = 0; t < 4; ++t) {
        int k = lane * 4 + t;
        const float* ck = CB + (size_t)k * DD;
        float E = emu_dot384_np(xr, ck);
        float s = __fadd_rn(__fsub_rn(xx, __fmul_rn(2.0f, E)), E2EMU[k]);
        if (s < best || (s == best && k < bidx)) { best = s; bidx = k; }
      }
#pragma unroll
      for (int m = 1; m < 64; m <<= 1) {
        float ob = __shfl_xor(best, m);
        int   oi = __shfl_xor(bidx, m);
        if (ob < best || (ob == best && oi < bidx)) { best = ob; bidx = oi; }
      }

      const int old = (int)IDXO[r];
      if (bidx != old) {
        const float* cn = CB + (size_t)bidx * DD;
        const float* co = CB + (size_t)old * DD;
        double dl = 0.0;
        for (int d = lane; d < DD; d += 64) {
          float xv = xr[d];
          float qn = cn[d], qo = co[d];
          Q[(size_t)r * DD + d] = qn;
          double en = (double)qn - (double)xv;
          double eo = (double)qo - (double)xv;
          dl += en * en - eo * eo;
        }
#pragma unroll
        for (int m = 1; m < 64; m <<= 1) dl += __shfl_xor(dl, m);
        if (lane == 0) {
          atomicAdd(DELTA, dl);
          IDXO[r] = (float)bidx;
        }
      }
    }
  }
}

// ---------------- loss finalize ----------------
__global__ void finalize_kernel(const double* __restrict__ p0, int n0, double w0,
                                const double* __restrict__ p1, int n1, double w1,
                                const double* __restrict__ p2, int n2, double w2,
                                const double* __restrict__ delta,
                                float* __restrict__ out) {
  __shared__ double red[4];
  int tid = threadIdx.x;
  double s0 = 0.0, s1 = 0.0, s2 = 0.0;
  for (int i = tid; i < n0; i += 256) s0 += p0[i];
  for (int i = tid; i < n1; i += 256) s1 += p1[i];
  for (int i = tid; i < n2; i += 256) s2 += p2[i];
  double v = s0 * w0 + s1 * w1 + s2 * w2;
#pragma unroll
  for (int m = 1; m < 64; m <<= 1) v += __shfl_xor(v, m);
  if ((tid & 63) == 0) red[tid >> 6] = v;
  __syncthreads();
  if (tid == 0)
    out[0] = (float)(red[0] + red[1] + red[2] + red[3]
                     + delta[0] * w0 + delta[1] * w1 + delta[2] * w2);
}

extern "C" void kernel_launch(void* const* d_in, const int* in_sizes, int n_in,
                              void* d_out, int out_size, void* d_ws, size_t ws_size,
                              hipStream_t stream) {
  const float* l0  = (const float*)d_in[0];
  const float* l1  = (const float*)d_in[1];
  const float* l2  = (const float*)d_in[2];
  const float* cb0 = (const float*)d_in[3];
  const float* cb1 = (const float*)d_in[4];
  const float* cb2 = (const float*)d_in[5];

  const size_t n_q0 = (size_t)in_sizes[0];
  const size_t n_q1 = (size_t)in_sizes[1];
  const size_t n_q2 = (size_t)in_sizes[2];
  const int r0 = (int)(n_q0 / DD);   // 65536
  const int r1 = (int)(n_q1 / DD);   // 262144
  const int r2 = (int)(n_q2 / DD);   // 262144

  float* out   = (float*)d_out;
  float* q0    = out;
  float* q1    = q0 + n_q0;
  float* q2    = q1 + n_q1;
  float* lossp = q2 + n_q2;
  float* idx0  = lossp + 1;
  float* idx1  = idx0 + r0;
  float* idx2  = idx1 + r1;

  // ws layout
  float*  e2    = (float*)d_ws;                          // 3*256 f32
  double* part  = (double*)((char*)d_ws + 4096);
  double* delta = (double*)((char*)d_ws + 4096 + 73728);
  unsigned char* flag0 = (unsigned char*)d_ws + 4096 + 73728 + 1024;
  unsigned char* flag1 = flag0 + r0;
  unsigned char* flag2 = flag1 + r1;
  // bf16-split fragment-ordered codebooks at 1 MiB: 3 x 384 KiB
  short* cbf0 = (short*)((char*)d_ws + (1 << 20));
  short* cbf1 = cbf0 + 196608;
  short* cbf2 = cbf1 + 196608;

  const int nb0 = r0 / TM, nb1 = r1 / TM, nb2 = r2 / TM;
  double* p0 = part;
  double* p1 = p0 + nb0;
  double* p2 = p1 + nb1;

  cb_norms_kernel<<<3, 256, 0, stream>>>(cb0, cb1, cb2, e2, delta);
  cb_split_kernel<<<48, 256, 0, stream>>>(cb0, cbf0);
  cb_split_kernel<<<48, 256, 0, stream>>>(cb1, cbf1);
  cb_split_kernel<<<48, 256, 0, stream>>>(cb2, cbf2);

  vq_main<<<nb0, 256, 0, stream>>>(l0, cb0, cbf0, e2 + 0 * KN, q0, idx0, flag0, p0);
  vq_main<<<nb1, 256, 0, stream>>>(l1, cb1, cbf1, e2 + 1 * KN, q1, idx1, flag1, p1);
  vq_main<<<nb2, 256, 0, stream>>>(l2, cb2, cbf2, e2 + 2 * KN, q2, idx2, flag2, p2);

  vq_refine<<<256, 256, 0, stream>>>(l0, cb0, e2 + 0 * KN, flag0, r0, q0, idx0, delta + 0);
  vq_refine<<<256, 256, 0, stream>>>(l1, cb1, e2 + 1 * KN, flag1, r1, q1, idx1, delta + 1);
  vq_refine<<<256, 256, 0, stream>>>(l2, cb2, e2 + 2 * KN, flag2, r2, q2, idx2, delta + 2);

  const double w0 = 0.05 / ((double)r0 * DD);
  const double w1 = 0.25 / ((double)r1 * DD);
  const double w2 = 0.60 / ((double)r2 * DD);
  finalize_kernel<<<1, 256, 0, stream>>>(p0, nb0, w0, p1, nb1, w1, p2, nb2, w2,
                                         delta, lossp);
}

// Round 10
// 958.954 us; speedup vs baseline: 50.0970x; 1.5319x over previous
//
#include <hip/hip_runtime.h>

static constexpr int KN  = 256;   // codebook entries
static constexpr int DD  = 384;   // feature dim
static constexpr int DD4 = 96;    // DD/4
static constexpr int TM  = 64;    // rows per block (MFMA v2: 64x256 block tile)
#define FLAG_MARGIN 0.005f

typedef __attribute__((ext_vector_type(8)))  short bf16x8;   // 8 bf16 = 4 VGPR
typedef __attribute__((ext_vector_type(16))) float f32x16;   // MFMA 32x32 acc
typedef __attribute__((ext_vector_type(4)))  short short4v;

__device__ __forceinline__ unsigned short f2bf_rne(float x) {
  unsigned u = __float_as_uint(x);
  return (unsigned short)((u + 0x7fffu + ((u >> 16) & 1u)) >> 16);
}

// ======== numpy-fp32 emulation helpers (VALIDATED round 4 — do not touch) ====
__device__ __forceinline__ float emu_sq_pairwise384(const float* __restrict__ p) {
  float S[4];
#pragma unroll
  for (int blk = 0; blk < 4; ++blk) {
    const float* b = p + blk * 96;
    float r[8];
#pragma unroll
    for (int l = 0; l < 8; ++l) r[l] = __fmul_rn(b[l], b[l]);
    for (int j = 8; j < 96; j += 8) {
#pragma unroll
      for (int l = 0; l < 8; ++l) r[l] = __fadd_rn(r[l], __fmul_rn(b[j + l], b[j + l]));
    }
    float t1 = __fadd_rn(__fadd_rn(r[0], r[1]), __fadd_rn(r[2], r[3]));
    float t2 = __fadd_rn(__fadd_rn(r[4], r[5]), __fadd_rn(r[6], r[7]));
    S[blk] = __fadd_rn(t1, t2);
  }
  return __fadd_rn(__fadd_rn(S[0], S[1]), __fadd_rn(S[2], S[3]));
}

__device__ __forceinline__ float emu_dot384_np(const float* __restrict__ x,
                                               const float* __restrict__ c) {
  float s[16];
#pragma unroll
  for (int t = 0; t < 16; ++t) s[t] = 0.f;
  for (int j = 0; j < 384; j += 16) {
#pragma unroll
    for (int t = 0; t < 16; ++t)
      s[t] = __fadd_rn(__fmul_rn(x[j + t], c[j + t]), s[t]);
  }
  float w0 = __fadd_rn(__fadd_rn(s[0], s[4]), __fadd_rn(s[8],  s[12]));
  float w1 = __fadd_rn(__fadd_rn(s[1], s[5]), __fadd_rn(s[9],  s[13]));
  float w2 = __fadd_rn(__fadd_rn(s[2], s[6]), __fadd_rn(s[10], s[14]));
  float w3 = __fadd_rn(__fadd_rn(s[3], s[7]), __fadd_rn(s[11], s[15]));
  return __fadd_rn(__fadd_rn(w0, w1), __fadd_rn(w2, w3));
}

// ---------------- codebook squared norms: exact numpy values ----------------
__global__ void cb_norms_kernel(const float* __restrict__ cb0,
                                const float* __restrict__ cb1,
                                const float* __restrict__ cb2,
                                float* __restrict__ e2,
                                double* __restrict__ delta) {
  int l = blockIdx.x;
  int k = threadIdx.x;
  const float* cb = (l == 0) ? cb0 : ((l == 1) ? cb1 : cb2);
  e2[l * KN + k] = emu_sq_pairwise384(cb + (size_t)k * DD);
  if (k == 0) delta[l] = 0.0;
}

// ---------------- codebook bf16-split, fragment-ordered --------------------
// frag layout: [chunk(12)][tile(8)][ks(2)][hl(2)] blocks of 1024B; within a
// block lane=(entry&31)+32*((k>>3)&1) holds 8 bf16 (16B) = its B-fragment.
__global__ __launch_bounds__(256) void cb_split_kernel(const float* __restrict__ cb,
                                                       short* __restrict__ frag) {
  int gid = blockIdx.x * 256 + threadIdx.x;       // 12288 = 256 entries * 48 groups
  int e = gid / 48;
  int g = gid - e * 48;                           // 8-k group
  const float4* s4 = reinterpret_cast<const float4*>(cb) + (size_t)e * 96 + g * 2;
  float4 v0 = s4[0], v1 = s4[1];
  float xs[8] = {v0.x, v0.y, v0.z, v0.w, v1.x, v1.y, v1.z, v1.w};
  short h[8], l[8];
#pragma unroll
  for (int i = 0; i < 8; ++i) {
    h[i] = (short)f2bf_rne(xs[i]);
    float hf = __uint_as_float((unsigned)(unsigned short)h[i] << 16);
    l[i] = (short)f2bf_rne(xs[i] - hf);
  }
  int c = g >> 2, rem = g & 3, ks = rem >> 1, hs = rem & 1;
  int t = e >> 5, lane = (e & 31) + (hs << 5);
  size_t blk = (((size_t)(c * 8 + t) * 2 + ks) * 2);   // h block index (1024B units)
  short* dh = frag + blk * 512 + lane * 8;
  short* dl = dh + 512;
  *reinterpret_cast<bf16x8*>(dh) = *reinterpret_cast<const bf16x8*>(h);
  *reinterpret_cast<bf16x8*>(dl) = *reinterpret_cast<const bf16x8*>(l);
}

// ---------------- phase 1: MFMA GEMM + argmin + flag ----------------
// 4 waves in 2x2: wave (wr,wc) owns rows wr*32..+31, cols wc*128..+127 as
// 4 tiles of 32x32 -> acc[4] = 64 AGPR (round 9: 128 AGPR -> 1 wave/SIMD).
// X-LDS fragment blocks padded to 1056B (halves at +528B) to kill the
// 16-way staging-write bank conflict (round 9: 9.4M conflict cycles).
__global__ __launch_bounds__(256) void vq_main(
    const float* __restrict__ X,
    const float* __restrict__ CBF32,
    const short* __restrict__ CBFRAG,
    const float* __restrict__ E2,
    float* __restrict__ Q,
    float* __restrict__ IDXO,
    unsigned char* __restrict__ FLAG,
    double* __restrict__ PART)
{
  __shared__ __align__(16) short cb_lds[16384];  // 32KB, [t(8)][ks(2)][hl(2)] 1KB blocks
  __shared__ __align__(16) short x_lds[4224];    // 8.25KB, 8 blocks x 528 shorts
  __shared__ int idx_s[TM];
  __shared__ float cand_b1[2][TM];
  __shared__ int   cand_i1[2][TM];
  __shared__ float cand_b2[2][TM];
  __shared__ double wred[4];

  const int tid  = threadIdx.x;
  const int wid  = tid >> 6, lane = tid & 63;
  const int lr   = lane & 31, hi = lane >> 5;
  const int wr   = wid >> 1, wc = wid & 1;
  const size_t row0 = (size_t)blockIdx.x * TM;
  const float4* X4 = reinterpret_cast<const float4*>(X);

  f32x16 acc[4];
  {
    f32x16 z;
#pragma unroll
    for (int i = 0; i < 16; ++i) z[i] = 0.f;
#pragma unroll
    for (int ct = 0; ct < 4; ++ct) acc[ct] = z;
  }

#pragma unroll 1
  for (int c = 0; c < 12; ++c) {
    // stage CB chunk: pure linear 32KB copy (fragment-ordered in ws, L2-hot)
    const float4* src = reinterpret_cast<const float4*>(CBFRAG) + (size_t)c * 2048 + tid;
    float4* cdst = reinterpret_cast<float4*>(cb_lds);
#pragma unroll
    for (int s = 0; s < 8; ++s) cdst[tid + s * 256] = src[s * 256];
    // stage X chunk: 64 rows x 32 k fp32 -> bf16 h/l, fragment-ordered, padded
#pragma unroll
    for (int i = 0; i < 2; ++i) {
      int idx = tid + i * 256;
      int r = idx >> 3, k4 = idx & 7;
      float4 v = X4[(row0 + (size_t)r) * DD4 + c * 8 + k4];
      float xs[4] = {v.x, v.y, v.z, v.w};
      short h[4], l[4];
#pragma unroll
      for (int e = 0; e < 4; ++e) {
        h[e] = (short)f2bf_rne(xs[e]);
        float hf = __uint_as_float((unsigned)(unsigned short)h[e] << 16);
        l[e] = (short)f2bf_rne(xs[e] - hf);
      }
      int rt = r >> 5, ks = k4 >> 2, hs = (k4 >> 1) & 1;
      int off_h = ((rt * 2 + ks) * 2) * 528 + hs * 264 + (r & 31) * 8 + (k4 & 1) * 4;
      *reinterpret_cast<short4v*>(&x_lds[off_h])       = *reinterpret_cast<short4v*>(h);
      *reinterpret_cast<short4v*>(&x_lds[off_h + 528]) = *reinterpret_cast<short4v*>(l);
    }
    __syncthreads();

#pragma unroll 1
    for (int ks = 0; ks < 2; ++ks) {
      const int abase = ((wr * 2 + ks) * 2) * 528 + hi * 264 + lr * 8;
      bf16x8 ah = *reinterpret_cast<const bf16x8*>(&x_lds[abase]);
      bf16x8 al = *reinterpret_cast<const bf16x8*>(&x_lds[abase + 528]);
      const bf16x8* bb = reinterpret_cast<const bf16x8*>(cb_lds);
#pragma unroll
      for (int ct = 0; ct < 4; ++ct) {
        int t = wc * 4 + ct;
        bf16x8 bh = bb[((t * 2 + ks) * 2 + 0) * 64 + lane];
        bf16x8 bl = bb[((t * 2 + ks) * 2 + 1) * 64 + lane];
        acc[ct] = __builtin_amdgcn_mfma_f32_32x32x16_bf16(ah, bh, acc[ct], 0, 0, 0);
        acc[ct] = __builtin_amdgcn_mfma_f32_32x32x16_bf16(ah, bl, acc[ct], 0, 0, 0);
        acc[ct] = __builtin_amdgcn_mfma_f32_32x32x16_bf16(al, bh, acc[ct], 0, 0, 0);
      }
    }
    __syncthreads();
  }

  // ---- argmin epilogue: D layout col=lane&31, row=(v&3)+8*(v>>2)+4*hi ----
  float e2v[4];
#pragma unroll
  for (int ct = 0; ct < 4; ++ct) e2v[ct] = E2[wc * 128 + ct * 32 + lr];

#pragma unroll
  for (int v = 0; v < 16; ++v) {
    int rloc = (v & 3) + 8 * (v >> 2) + 4 * hi;
    int row = wr * 32 + rloc;
    float b1 = 1e30f; int i1 = 0x7fffffff;
#pragma unroll
    for (int ct = 0; ct < 4; ++ct) {
      float sc = e2v[ct] - 2.0f * acc[ct][v];
      int col = wc * 128 + ct * 32 + lr;
      if (sc < b1) { b1 = sc; i1 = col; }
    }
#pragma unroll
    for (int m = 1; m < 32; m <<= 1) {     // within 32-lane halves (hi preserved)
      float ob = __shfl_xor(b1, m);
      int   oi = __shfl_xor(i1, m);
      if (ob < b1 || (ob == b1 && oi < i1)) { b1 = ob; i1 = oi; }
    }
    float b2 = 1e30f;
#pragma unroll
    for (int ct = 0; ct < 4; ++ct) {
      float sc = e2v[ct] - 2.0f * acc[ct][v];
      int col = wc * 128 + ct * 32 + lr;
      if (col != i1 && sc < b2) b2 = sc;
    }
#pragma unroll
    for (int m = 1; m < 32; m <<= 1) {
      float ob = __shfl_xor(b2, m);
      if (ob < b2) b2 = ob;
    }
    if (lr == 0) {
      cand_b1[wc][row] = b1; cand_i1[wc][row] = i1; cand_b2[wc][row] = b2;
    }
  }
  __syncthreads();

  // merge col-halves + write idx/flag (one thread per row)
  if (tid < TM) {
    float a1 = cand_b1[0][tid], a2 = cand_b2[0][tid];
    int   ai = cand_i1[0][tid];
    float c1 = cand_b1[1][tid], c2 = cand_b2[1][tid];
    int   ci = cand_i1[1][tid];
    float b1; int i1; float b2;
    if (c1 < a1 || (c1 == a1 && ci < ai)) {
      b1 = c1; i1 = ci; b2 = (a1 < c2) ? a1 : c2;
    } else {
      b1 = a1; i1 = ai; b2 = (c1 < a2) ? c1 : a2;
    }
    idx_s[tid] = i1;
    IDXO[row0 + tid] = (float)i1;
    FLAG[row0 + tid] = (b2 - b1 < FLAG_MARGIN) ? 1 : 0;
  }
  __syncthreads();

  // ---- outputs: q = cb[idx] (fp32 gather), loss partial ----
  const float4* CB4 = reinterpret_cast<const float4*>(CBF32);
  float4* Q4 = reinterpret_cast<float4*>(Q);
  float lsum = 0.f;
  for (int i = tid; i < TM * DD4; i += 256) {
    int r = i / DD4;
    int cc = i - r * DD4;
    int k = idx_s[r];
    float4 qv = CB4[(size_t)k * DD4 + cc];
    float4 xv = X4[(row0 + (size_t)r) * DD4 + cc];
    float dx = qv.x - xv.x, dy = qv.y - xv.y, dz = qv.z - xv.z, dw = qv.w - xv.w;
    lsum += dx * dx + dy * dy + dz * dz + dw * dw;
    Q4[(row0 + (size_t)r) * DD4 + cc] = qv;
  }
#pragma unroll
  for (int m = 1; m < 64; m <<= 1) lsum += __shfl_xor(lsum, m);
  if ((tid & 63) == 0) wred[tid >> 6] = (double)lsum;
  __syncthreads();
  if (tid == 0) PART[blockIdx.x] = wred[0] + wred[1] + wred[2] + wred[3];
}

// ---------------- phase 2: numpy-exact refine of flagged rows ----------------
__global__ __launch_bounds__(256) void vq_refine(
    const float* __restrict__ X,
    const float* __restrict__ CB,
    const float* __restrict__ E2EMU,
    const unsigned char* __restrict__ FLAG,
    int nrows,
    float* __restrict__ Q,
    float* __restrict__ IDXO,
    double* __restrict__ DELTA)
{
  const int lane   = threadIdx.x & 63;
  const int gwave  = (blockIdx.x * blockDim.x + threadIdx.x) >> 6;
  const int nwaves = (gridDim.x * blockDim.x) >> 6;

  for (int base = gwave * 64; base < nrows; base += nwaves * 64) {
    int rr = base + lane;
    unsigned char f = (rr < nrows) ? FLAG[rr] : 0;
    unsigned long long mask = __ballot(f != 0);
    while (mask) {
      int bit = __ffsll((long long)mask) - 1;
      mask &= mask - 1;
      const int r = base + bit;
      const float* xr = X + (size_t)r * DD;
      const float xx = emu_sq_pairwise384(xr);

      float best = 1e30f; int bidx = 0x7fffffff;
#pragma unroll
      for (int t = 0; t < 4; ++t) {
        int k = lane * 4 + t;
        const float* ck = CB + (size_t)k * DD;
        float E = emu_dot384_np(xr, ck);
        float s = __fadd_rn(__fsub_rn(xx, __fmul_rn(2.0f, E)), E2EMU[k]);
        if (s < best || (s == best && k < bidx)) { best = s; bidx = k; }
      }
#pragma unroll
      for (int m = 1; m < 64; m <<= 1) {
        float ob = __shfl_xor(best, m);
        int   oi = __shfl_xor(bidx, m);
        if (ob < best || (ob == best && oi < bidx)) { best = ob; bidx = oi; }
      }

      const int old = (int)IDXO[r];
      if (bidx != old) {
        const float* cn = CB + (size_t)bidx * DD;
        const float* co = CB + (size_t)old * DD;
        double dl = 0.0;
        for (int d = lane; d < DD; d += 64) {
          float xv = xr[d];
          float qn = cn[d], qo = co[d];
          Q[(size_t)r * DD + d] = qn;
          double en = (double)qn - (double)xv;
          double eo = (double)qo - (double)xv;
          dl += en * en - eo * eo;
        }
#pragma unroll
        for (int m = 1; m < 64; m <<= 1) dl += __shfl_xor(dl, m);
        if (lane == 0) {
          atomicAdd(DELTA, dl);
          IDXO[r] = (float)bidx;
        }
      }
    }
  }
}

// ---------------- loss finalize ----------------
__global__ void finalize_kernel(const double* __restrict__ p0, int n0, double w0,
                                const double* __restrict__ p1, int n1, double w1,
                                const double* __restrict__ p2, int n2, double w2,
                                const double* __restrict__ delta,
                                float* __restrict__ out) {
  __shared__ double red[4];
  int tid = threadIdx.x;
  double s0 = 0.0, s1 = 0.0, s2 = 0.0;
  for (int i = tid; i < n0; i += 256) s0 += p0[i];
  for (int i = tid; i < n1; i += 256) s1 += p1[i];
  for (int i = tid; i < n2; i += 256) s2 += p2[i];
  double v = s0 * w0 + s1 * w1 + s2 * w2;
#pragma unroll
  for (int m = 1; m < 64; m <<= 1) v += __shfl_xor(v, m);
  if ((tid & 63) == 0) red[tid >> 6] = v;
  __syncthreads();
  if (tid == 0)
    out[0] = (float)(red[0] + red[1] + red[2] + red[3]
                     + delta[0] * w0 + delta[1] * w1 + delta[2] * w2);
}

extern "C" void kernel_launch(void* const* d_in, const int* in_sizes, int n_in,
                              void* d_out, int out_size, void* d_ws, size_t ws_size,
                              hipStream_t stream) {
  const float* l0  = (const float*)d_in[0];
  const float* l1  = (const float*)d_in[1];
  const float* l2  = (const float*)d_in[2];
  const float* cb0 = (const float*)d_in[3];
  const float* cb1 = (const float*)d_in[4];
  const float* cb2 = (const float*)d_in[5];

  const size_t n_q0 = (size_t)in_sizes[0];
  const size_t n_q1 = (size_t)in_sizes[1];
  const size_t n_q2 = (size_t)in_sizes[2];
  const int r0 = (int)(n_q0 / DD);   // 65536
  const int r1 = (int)(n_q1 / DD);   // 262144
  const int r2 = (int)(n_q2 / DD);   // 262144

  float* out   = (float*)d_out;
  float* q0    = out;
  float* q1    = q0 + n_q0;
  float* q2    = q1 + n_q1;
  float* lossp = q2 + n_q2;
  float* idx0  = lossp + 1;
  float* idx1  = idx0 + r0;
  float* idx2  = idx1 + r1;

  // ws layout
  float*  e2    = (float*)d_ws;                          // 3*256 f32
  double* part  = (double*)((char*)d_ws + 4096);         // 9216 doubles
  double* delta = (double*)((char*)d_ws + 4096 + 73728);
  unsigned char* flag0 = (unsigned char*)d_ws + 4096 + 73728 + 1024;
  unsigned char* flag1 = flag0 + r0;
  unsigned char* flag2 = flag1 + r1;
  // bf16-split fragment-ordered codebooks at 1 MiB: 3 x 384 KiB
  short* cbf0 = (short*)((char*)d_ws + (1 << 20));
  short* cbf1 = cbf0 + 196608;
  short* cbf2 = cbf1 + 196608;

  const int nb0 = r0 / TM, nb1 = r1 / TM, nb2 = r2 / TM;   // 1024/4096/4096
  double* p0 = part;
  double* p1 = p0 + nb0;
  double* p2 = p1 + nb1;

  cb_norms_kernel<<<3, 256, 0, stream>>>(cb0, cb1, cb2, e2, delta);
  cb_split_kernel<<<48, 256, 0, stream>>>(cb0, cbf0);
  cb_split_kernel<<<48, 256, 0, stream>>>(cb1, cbf1);
  cb_split_kernel<<<48, 256, 0, stream>>>(cb2, cbf2);

  vq_main<<<nb0, 256, 0, stream>>>(l0, cb0, cbf0, e2 + 0 * KN, q0, idx0, flag0, p0);
  vq_main<<<nb1, 256, 0, stream>>>(l1, cb1, cbf1, e2 + 1 * KN, q1, idx1, flag1, p1);
  vq_main<<<nb2, 256, 0, stream>>>(l2, cb2, cbf2, e2 + 2 * KN, q2, idx2, flag2, p2);

  vq_refine<<<256, 256, 0, stream>>>(l0, cb0, e2 + 0 * KN, flag0, r0, q0, idx0, delta + 0);
  vq_refine<<<256, 256, 0, stream>>>(l1, cb1, e2 + 1 * KN, flag1, r1, q1, idx1, delta + 1);
  vq_refine<<<256, 256, 0, stream>>>(l2, cb2, e2 + 2 * KN, flag2, r2, q2, idx2, delta + 2);

  const double w0 = 0.05 / ((double)r0 * DD);
  const double w1 = 0.25 / ((double)r1 * DD);
  const double w2 = 0.60 / ((double)r2 * DD);
  finalize_kernel<<<1, 256, 0, stream>>>(p0, nb0, w0, p1, nb1, w1, p2, nb2, w2,
                                         delta, lossp);
}

// Round 11
// 818.428 us; speedup vs baseline: 58.6988x; 1.1717x over previous
//
#include <hip/hip_runtime.h>

static constexpr int KN  = 256;   // codebook entries
static constexpr int DD  = 384;   // feature dim
static constexpr int DD4 = 96;    // DD/4
static constexpr int TM  = 64;    // rows per block (64x256 block tile)
#define FLAG_MARGIN 0.005f

typedef __attribute__((ext_vector_type(8)))  short bf16x8;   // 8 bf16 = 4 VGPR
typedef __attribute__((ext_vector_type(16))) float f32x16;   // MFMA 32x32 acc
typedef __attribute__((ext_vector_type(4)))  short short4v;

__device__ __forceinline__ unsigned short f2bf_rne(float x) {
  unsigned u = __float_as_uint(x);
  return (unsigned short)((u + 0x7fffu + ((u >> 16) & 1u)) >> 16);
}

// async global->LDS, 16B per lane (dest = wave-uniform base + lane*16)
__device__ __forceinline__ void g2lds16(const void* g, void* l) {
  __builtin_amdgcn_global_load_lds(
      (const __attribute__((address_space(1))) unsigned int*)g,
      (__attribute__((address_space(3))) unsigned int*)l, 16, 0, 0);
}

// ======== numpy-fp32 emulation helpers (VALIDATED round 4 — do not touch) ====
__device__ __forceinline__ float emu_sq_pairwise384(const float* __restrict__ p) {
  float S[4];
#pragma unroll
  for (int blk = 0; blk < 4; ++blk) {
    const float* b = p + blk * 96;
    float r[8];
#pragma unroll
    for (int l = 0; l < 8; ++l) r[l] = __fmul_rn(b[l], b[l]);
    for (int j = 8; j < 96; j += 8) {
#pragma unroll
      for (int l = 0; l < 8; ++l) r[l] = __fadd_rn(r[l], __fmul_rn(b[j + l], b[j + l]));
    }
    float t1 = __fadd_rn(__fadd_rn(r[0], r[1]), __fadd_rn(r[2], r[3]));
    float t2 = __fadd_rn(__fadd_rn(r[4], r[5]), __fadd_rn(r[6], r[7]));
    S[blk] = __fadd_rn(t1, t2);
  }
  return __fadd_rn(__fadd_rn(S[0], S[1]), __fadd_rn(S[2], S[3]));
}

__device__ __forceinline__ float emu_dot384_np(const float* __restrict__ x,
                                               const float* __restrict__ c) {
  float s[16];
#pragma unroll
  for (int t = 0; t < 16; ++t) s[t] = 0.f;
  for (int j = 0; j < 384; j += 16) {
#pragma unroll
    for (int t = 0; t < 16; ++t)
      s[t] = __fadd_rn(__fmul_rn(x[j + t], c[j + t]), s[t]);
  }
  float w0 = __fadd_rn(__fadd_rn(s[0], s[4]), __fadd_rn(s[8],  s[12]));
  float w1 = __fadd_rn(__fadd_rn(s[1], s[5]), __fadd_rn(s[9],  s[13]));
  float w2 = __fadd_rn(__fadd_rn(s[2], s[6]), __fadd_rn(s[10], s[14]));
  float w3 = __fadd_rn(__fadd_rn(s[3], s[7]), __fadd_rn(s[11], s[15]));
  return __fadd_rn(__fadd_rn(w0, w1), __fadd_rn(w2, w3));
}

// ---------------- codebook squared norms: exact numpy values ----------------
__global__ void cb_norms_kernel(const float* __restrict__ cb0,
                                const float* __restrict__ cb1,
                                const float* __restrict__ cb2,
                                float* __restrict__ e2,
                                double* __restrict__ delta) {
  int l = blockIdx.x;
  int k = threadIdx.x;
  const float* cb = (l == 0) ? cb0 : ((l == 1) ? cb1 : cb2);
  e2[l * KN + k] = emu_sq_pairwise384(cb + (size_t)k * DD);
  if (k == 0) delta[l] = 0.0;
}

// ---------------- codebook bf16-split, fragment-ordered (all 3 levels) ------
__global__ __launch_bounds__(256) void cb_split_kernel(const float* __restrict__ c0,
                                                       const float* __restrict__ c1,
                                                       const float* __restrict__ c2,
                                                       short* __restrict__ f0,
                                                       short* __restrict__ f1,
                                                       short* __restrict__ f2) {
  int lvl = blockIdx.x / 48;
  int blk48 = blockIdx.x - lvl * 48;
  const float* cb = (lvl == 0) ? c0 : ((lvl == 1) ? c1 : c2);
  short* frag     = (lvl == 0) ? f0 : ((lvl == 1) ? f1 : f2);
  int gid = blk48 * 256 + threadIdx.x;            // 12288 = 256 entries * 48 groups
  int e = gid / 48;
  int g = gid - e * 48;
  const float4* s4 = reinterpret_cast<const float4*>(cb) + (size_t)e * 96 + g * 2;
  float4 v0 = s4[0], v1 = s4[1];
  float xs[8] = {v0.x, v0.y, v0.z, v0.w, v1.x, v1.y, v1.z, v1.w};
  short h[8], l[8];
#pragma unroll
  for (int i = 0; i < 8; ++i) {
    h[i] = (short)f2bf_rne(xs[i]);
    float hf = __uint_as_float((unsigned)(unsigned short)h[i] << 16);
    l[i] = (short)f2bf_rne(xs[i] - hf);
  }
  int c = g >> 2, rem = g & 3, ks = rem >> 1, hs = rem & 1;
  int t = e >> 5, lane = (e & 31) + (hs << 5);
  size_t blk = (((size_t)(c * 8 + t) * 2 + ks) * 2);
  short* dh = frag + blk * 512 + lane * 8;
  short* dl = dh + 512;
  *reinterpret_cast<bf16x8*>(dh) = *reinterpret_cast<const bf16x8*>(h);
  *reinterpret_cast<bf16x8*>(dl) = *reinterpret_cast<const bf16x8*>(l);
}

// ---------------- phase 1: MFMA GEMM + argmin + flag + loss-from-scores -----
__global__ __launch_bounds__(256) void vq_main(
    const float* __restrict__ X,
    const float* __restrict__ CBF32,
    const short* __restrict__ CBFRAG,
    const float* __restrict__ E2,
    float* __restrict__ Q,
    float* __restrict__ IDXO,
    unsigned char* __restrict__ FLAG,
    double* __restrict__ PART)
{
  __shared__ __align__(16) short cb_lds[16384];  // 32KB, [t(8)][ks(2)][hl(2)] 1KB blocks
  __shared__ __align__(16) short x_lds[4224];    // 8.25KB, 8 blocks x 528 shorts
  __shared__ int idx_s[TM];
  __shared__ float xx_s[TM];
  __shared__ float cand_b1[2][TM];
  __shared__ int   cand_i1[2][TM];
  __shared__ float cand_b2[2][TM];

  const int tid  = threadIdx.x;
  const int wid  = tid >> 6, lane = tid & 63;
  const int lr   = lane & 31, hi = lane >> 5;
  const int wr   = wid >> 1, wc = wid & 1;
  const size_t row0 = (size_t)blockIdx.x * TM;
  const float4* X4 = reinterpret_cast<const float4*>(X);

  f32x16 acc[4];
  {
    f32x16 z;
#pragma unroll
    for (int i = 0; i < 16; ++i) z[i] = 0.f;
#pragma unroll
    for (int ct = 0; ct < 4; ++ct) acc[ct] = z;
  }
  float xx0 = 0.f, xx1 = 0.f;   // row-norm partials (rows tid>>3 and (tid>>3)+32)

#pragma unroll 1
  for (int c = 0; c < 12; ++c) {
    // stage CB chunk: async global->LDS, 8 x 16B per thread, linear
    {
      const char* gsrc = (const char*)CBFRAG + (size_t)c * 32768 + tid * 16;
#pragma unroll
      for (int s = 0; s < 8; ++s)
        g2lds16(gsrc + s * 4096, (char*)cb_lds + tid * 16 + s * 4096);
    }
    // stage X chunk: 64 rows x 32 k fp32 -> bf16 h/l, fragment-ordered, padded
#pragma unroll
    for (int i = 0; i < 2; ++i) {
      int idx = tid + i * 256;
      int r = idx >> 3, k4 = idx & 7;
      float4 v = X4[(row0 + (size_t)r) * DD4 + c * 8 + k4];
      float pp = v.x * v.x + v.y * v.y + v.z * v.z + v.w * v.w;
      if (i == 0) xx0 += pp; else xx1 += pp;
      float xs[4] = {v.x, v.y, v.z, v.w};
      short h[4], l[4];
#pragma unroll
      for (int e = 0; e < 4; ++e) {
        h[e] = (short)f2bf_rne(xs[e]);
        float hf = __uint_as_float((unsigned)(unsigned short)h[e] << 16);
        l[e] = (short)f2bf_rne(xs[e] - hf);
      }
      int rt = r >> 5, ks = k4 >> 2, hs = (k4 >> 1) & 1;
      int off_h = ((rt * 2 + ks) * 2) * 528 + hs * 264 + (r & 31) * 8 + (k4 & 1) * 4;
      *reinterpret_cast<short4v*>(&x_lds[off_h])       = *reinterpret_cast<short4v*>(h);
      *reinterpret_cast<short4v*>(&x_lds[off_h + 528]) = *reinterpret_cast<short4v*>(l);
    }
    __syncthreads();

#pragma unroll 1
    for (int ks = 0; ks < 2; ++ks) {
      const int abase = ((wr * 2 + ks) * 2) * 528 + hi * 264 + lr * 8;
      bf16x8 ah = *reinterpret_cast<const bf16x8*>(&x_lds[abase]);
      bf16x8 al = *reinterpret_cast<const bf16x8*>(&x_lds[abase + 528]);
      const bf16x8* bb = reinterpret_cast<const bf16x8*>(cb_lds);
#pragma unroll
      for (int ct = 0; ct < 4; ++ct) {
        int t = wc * 4 + ct;
        bf16x8 bh = bb[((t * 2 + ks) * 2 + 0) * 64 + lane];
        bf16x8 bl = bb[((t * 2 + ks) * 2 + 1) * 64 + lane];
        acc[ct] = __builtin_amdgcn_mfma_f32_32x32x16_bf16(ah, bh, acc[ct], 0, 0, 0);
        acc[ct] = __builtin_amdgcn_mfma_f32_32x32x16_bf16(ah, bl, acc[ct], 0, 0, 0);
        acc[ct] = __builtin_amdgcn_mfma_f32_32x32x16_bf16(al, bh, acc[ct], 0, 0, 0);
      }
    }
    __syncthreads();
  }

  // ---- row norms: reduce 8-thread groups, park in LDS ----
#pragma unroll
  for (int m = 1; m < 8; m <<= 1) {
    xx0 += __shfl_xor(xx0, m);
    xx1 += __shfl_xor(xx1, m);
  }
  if ((lane & 7) == 0) {
    xx_s[tid >> 3]        = xx0;
    xx_s[(tid >> 3) + 32] = xx1;
  }

  // ---- argmin epilogue: D layout col=lane&31, row=(v&3)+8*(v>>2)+4*hi ----
  float e2v[4];
#pragma unroll
  for (int ct = 0; ct < 4; ++ct) e2v[ct] = E2[wc * 128 + ct * 32 + lr];

#pragma unroll
  for (int v = 0; v < 16; ++v) {
    int rloc = (v & 3) + 8 * (v >> 2) + 4 * hi;
    int row = wr * 32 + rloc;
    float b1 = 1e30f; int i1 = 0x7fffffff;
#pragma unroll
    for (int ct = 0; ct < 4; ++ct) {
      float sc = e2v[ct] - 2.0f * acc[ct][v];
      int col = wc * 128 + ct * 32 + lr;
      if (sc < b1) { b1 = sc; i1 = col; }
    }
#pragma unroll
    for (int m = 1; m < 32; m <<= 1) {     // within 32-lane halves (hi preserved)
      float ob = __shfl_xor(b1, m);
      int   oi = __shfl_xor(i1, m);
      if (ob < b1 || (ob == b1 && oi < i1)) { b1 = ob; i1 = oi; }
    }
    float b2 = 1e30f;
#pragma unroll
    for (int ct = 0; ct < 4; ++ct) {
      float sc = e2v[ct] - 2.0f * acc[ct][v];
      int col = wc * 128 + ct * 32 + lr;
      if (col != i1 && sc < b2) b2 = sc;
    }
#pragma unroll
    for (int m = 1; m < 32; m <<= 1) {
      float ob = __shfl_xor(b2, m);
      if (ob < b2) b2 = ob;
    }
    if (lr == 0) {
      cand_b1[wc][row] = b1; cand_i1[wc][row] = i1; cand_b2[wc][row] = b2;
    }
  }
  __syncthreads();

  // merge col-halves; idx/flag; per-row loss = xx + b1 (wave 0 only)
  double lrow = 0.0;
  if (tid < TM) {
    float a1 = cand_b1[0][tid], a2 = cand_b2[0][tid];
    int   ai = cand_i1[0][tid];
    float c1 = cand_b1[1][tid], c2 = cand_b2[1][tid];
    int   ci = cand_i1[1][tid];
    float b1; int i1; float b2;
    if (c1 < a1 || (c1 == a1 && ci < ai)) {
      b1 = c1; i1 = ci; b2 = (a1 < c2) ? a1 : c2;
    } else {
      b1 = a1; i1 = ai; b2 = (c1 < a2) ? c1 : a2;
    }
    idx_s[tid] = i1;
    IDXO[row0 + tid] = (float)i1;
    FLAG[row0 + tid] = (b2 - b1 < FLAG_MARGIN) ? 1 : 0;
    lrow = (double)xx_s[tid] + (double)b1;
  }
  if (tid < 64) {
#pragma unroll
    for (int m = 1; m < 64; m <<= 1) lrow += __shfl_xor(lrow, m);
    if (tid == 0) PART[blockIdx.x] = lrow;
  }
  __syncthreads();

  // ---- output: q = cb[idx] (pure gather+write; no X re-read) ----
  const float4* CB4 = reinterpret_cast<const float4*>(CBF32);
  float4* Q4 = reinterpret_cast<float4*>(Q);
  for (int i = tid; i < TM * DD4; i += 256) {
    int r = i / DD4;
    int cc = i - r * DD4;
    Q4[(row0 + (size_t)r) * DD4 + cc] = CB4[(size_t)idx_s[r] * DD4 + cc];
  }
}

// ---------------- phase 2: numpy-exact refine, all 3 levels, one launch -----
__global__ __launch_bounds__(256) void vq_refine(
    const float* __restrict__ X0, const float* __restrict__ X1, const float* __restrict__ X2,
    const float* __restrict__ C0, const float* __restrict__ C1, const float* __restrict__ C2,
    const float* __restrict__ E2A,
    const unsigned char* __restrict__ F0, const unsigned char* __restrict__ F1,
    const unsigned char* __restrict__ F2,
    int r0, int r1, int r2,
    float* __restrict__ Q0, float* __restrict__ Q1, float* __restrict__ Q2,
    float* __restrict__ I0, float* __restrict__ I1, float* __restrict__ I2,
    double* __restrict__ DELTA)
{
  const int lane   = threadIdx.x & 63;
  const int gwave  = (blockIdx.x * blockDim.x + threadIdx.x) >> 6;
  const int nwaves = (gridDim.x * blockDim.x) >> 6;
  const int ntot = r0 + r1 + r2;

  for (int base = gwave * 64; base < ntot; base += nwaves * 64) {
    // levels are 64-row aligned, so a window never straddles
    int lvl, lb;
    const float *X, *CB; const unsigned char* FLAG; float *Q, *IDXO;
    if (base < r0)           { lvl = 0; lb = base;            X = X0; CB = C0; FLAG = F0; Q = Q0; IDXO = I0; }
    else if (base < r0 + r1) { lvl = 1; lb = base - r0;       X = X1; CB = C1; FLAG = F1; Q = Q1; IDXO = I1; }
    else                     { lvl = 2; lb = base - r0 - r1;  X = X2; CB = C2; FLAG = F2; Q = Q2; IDXO = I2; }
    const float* E2EMU = E2A + lvl * KN;

    unsigned char f = FLAG[lb + lane];
    unsigned long long mask = __ballot(f != 0);
    while (mask) {
      int bit = __ffsll((long long)mask) - 1;
      mask &= mask - 1;
      const int r = lb + bit;
      const float* xr = X + (size_t)r * DD;
      const float xx = emu_sq_pairwise384(xr);

      float best = 1e30f; int bidx = 0x7fffffff;
#pragma unroll
      for (int t = 0; t < 4; ++t) {
        int k = lane * 4 + t;
        const float* ck = CB + (size_t)k * DD;
        float E = emu_dot384_np(xr, ck);
        float s = __fadd_rn(__fsub_rn(xx, __fmul_rn(2.0f, E)), E2EMU[k]);
        if (s < best || (s == best && k < bidx)) { best = s; bidx = k; }
      }
#pragma unroll
      for (int m = 1; m < 64; m <<= 1) {
        float ob = __shfl_xor(best, m);
        int   oi = __shfl_xor(bidx, m);
        if (ob < best || (ob == best && oi < bidx)) { best = ob; bidx = oi; }
      }

      const int old = (int)IDXO[r];
      if (bidx != old) {
        const float* cn = CB + (size_t)bidx * DD;
        const float* co = CB + (size_t)old * DD;
        double dl = 0.0;
        for (int d = lane; d < DD; d += 64) {
          float xv = xr[d];
          float qn = cn[d], qo = co[d];
          Q[(size_t)r * DD + d] = qn;
          double en = (double)qn - (double)xv;
          double eo = (double)qo - (double)xv;
          dl += en * en - eo * eo;
        }
#pragma unroll
        for (int m = 1; m < 64; m <<= 1) dl += __shfl_xor(dl, m);
        if (lane == 0) {
          atomicAdd(DELTA + lvl, dl);
          IDXO[r] = (float)bidx;
        }
      }
    }
  }
}

// ---------------- loss finalize ----------------
__global__ void finalize_kernel(const double* __restrict__ p0, int n0, double w0,
                                const double* __restrict__ p1, int n1, double w1,
                                const double* __restrict__ p2, int n2, double w2,
                                const double* __restrict__ delta,
                                float* __restrict__ out) {
  __shared__ double red[4];
  int tid = threadIdx.x;
  double s0 = 0.0, s1 = 0.0, s2 = 0.0;
  for (int i = tid; i < n0; i += 256) s0 += p0[i];
  for (int i = tid; i < n1; i += 256) s1 += p1[i];
  for (int i = tid; i < n2; i += 256) s2 += p2[i];
  double v = s0 * w0 + s1 * w1 + s2 * w2;
#pragma unroll
  for (int m = 1; m < 64; m <<= 1) v += __shfl_xor(v, m);
  if ((tid & 63) == 0) red[tid >> 6] = v;
  __syncthreads();
  if (tid == 0)
    out[0] = (float)(red[0] + red[1] + red[2] + red[3]
                     + delta[0] * w0 + delta[1] * w1 + delta[2] * w2);
}

extern "C" void kernel_launch(void* const* d_in, const int* in_sizes, int n_in,
                              void* d_out, int out_size, void* d_ws, size_t ws_size,
                              hipStream_t stream) {
  const float* l0  = (const float*)d_in[0];
  const float* l1  = (const float*)d_in[1];
  const float* l2  = (const float*)d_in[2];
  const float* cb0 = (const float*)d_in[3];
  const float* cb1 = (const float*)d_in[4];
  const float* cb2 = (const float*)d_in[5];

  const size_t n_q0 = (size_t)in_sizes[0];
  const size_t n_q1 = (size_t)in_sizes[1];
  const size_t n_q2 = (size_t)in_sizes[2];
  const int r0 = (int)(n_q0 / DD);   // 65536
  const int r1 = (int)(n_q1 / DD);   // 262144
  const int r2 = (int)(n_q2 / DD);   // 262144

  float* out   = (float*)d_out;
  float* q0    = out;
  float* q1    = q0 + n_q0;
  float* q2    = q1 + n_q1;
  float* lossp = q2 + n_q2;
  float* idx0  = lossp + 1;
  float* idx1  = idx0 + r0;
  float* idx2  = idx1 + r1;

  // ws layout
  float*  e2    = (float*)d_ws;                          // 3*256 f32
  double* part  = (double*)((char*)d_ws + 4096);         // 9216 doubles
  double* delta = (double*)((char*)d_ws + 4096 + 73728);
  unsigned char* flag0 = (unsigned char*)d_ws + 4096 + 73728 + 1024;
  unsigned char* flag1 = flag0 + r0;
  unsigned char* flag2 = flag1 + r1;
  short* cbf0 = (short*)((char*)d_ws + (1 << 20));       // 3 x 384 KiB
  short* cbf1 = cbf0 + 196608;
  short* cbf2 = cbf1 + 196608;

  const int nb0 = r0 / TM, nb1 = r1 / TM, nb2 = r2 / TM;
  double* p0 = part;
  double* p1 = p0 + nb0;
  double* p2 = p1 + nb1;

  cb_norms_kernel<<<3, 256, 0, stream>>>(cb0, cb1, cb2, e2, delta);
  cb_split_kernel<<<144, 256, 0, stream>>>(cb0, cb1, cb2, cbf0, cbf1, cbf2);

  vq_main<<<nb0, 256, 0, stream>>>(l0, cb0, cbf0, e2 + 0 * KN, q0, idx0, flag0, p0);
  vq_main<<<nb1, 256, 0, stream>>>(l1, cb1, cbf1, e2 + 1 * KN, q1, idx1, flag1, p1);
  vq_main<<<nb2, 256, 0, stream>>>(l2, cb2, cbf2, e2 + 2 * KN, q2, idx2, flag2, p2);

  vq_refine<<<512, 256, 0, stream>>>(l0, l1, l2, cb0, cb1, cb2, e2,
                                     flag0, flag1, flag2, r0, r1, r2,
                                     q0, q1, q2, idx0, idx1, idx2, delta);

  const double w0 = 0.05 / ((double)r0 * DD);
  const double w1 = 0.25 / ((double)r1 * DD);
  const double w2 = 0.60 / ((double)r2 * DD);
  finalize_kernel<<<1, 256, 0, stream>>>(p0, nb0, w0, p1, nb1, w1, p2, nb2, w2,
                                         delta, lossp);
}

// Round 12
// 770.973 us; speedup vs baseline: 62.3118x; 1.0616x over previous
//
#include <hip/hip_runtime.h>

static constexpr int KN  = 256;   // codebook entries
static constexpr int DD  = 384;   // feature dim
static constexpr int DD4 = 96;    // DD/4
static constexpr int TM  = 64;    // rows per block (64x256 block tile)
#define FLAG_MARGIN 0.005f

typedef __attribute__((ext_vector_type(8)))  short bf16x8;   // 8 bf16 = 4 VGPR
typedef __attribute__((ext_vector_type(16))) float f32x16;   // MFMA 32x32 acc
typedef __attribute__((ext_vector_type(4)))  short short4v;

__device__ __forceinline__ unsigned short f2bf_rne(float x) {
  unsigned u = __float_as_uint(x);
  return (unsigned short)((u + 0x7fffu + ((u >> 16) & 1u)) >> 16);
}

// async global->LDS, 16B per lane (dest = wave-uniform base + lane*16)
__device__ __forceinline__ void g2lds16(const void* g, void* l) {
  __builtin_amdgcn_global_load_lds(
      (const __attribute__((address_space(1))) unsigned int*)g,
      (__attribute__((address_space(3))) unsigned int*)l, 16, 0, 0);
}

// ======== numpy-fp32 emulation helpers (VALIDATED round 4 — do not touch) ====
__device__ __forceinline__ float emu_sq_pairwise384(const float* __restrict__ p) {
  float S[4];
#pragma unroll
  for (int blk = 0; blk < 4; ++blk) {
    const float* b = p + blk * 96;
    float r[8];
#pragma unroll
    for (int l = 0; l < 8; ++l) r[l] = __fmul_rn(b[l], b[l]);
    for (int j = 8; j < 96; j += 8) {
#pragma unroll
      for (int l = 0; l < 8; ++l) r[l] = __fadd_rn(r[l], __fmul_rn(b[j + l], b[j + l]));
    }
    float t1 = __fadd_rn(__fadd_rn(r[0], r[1]), __fadd_rn(r[2], r[3]));
    float t2 = __fadd_rn(__fadd_rn(r[4], r[5]), __fadd_rn(r[6], r[7]));
    S[blk] = __fadd_rn(t1, t2);
  }
  return __fadd_rn(__fadd_rn(S[0], S[1]), __fadd_rn(S[2], S[3]));
}

__device__ __forceinline__ float emu_dot384_np(const float* __restrict__ x,
                                               const float* __restrict__ c) {
  float s[16];
#pragma unroll
  for (int t = 0; t < 16; ++t) s[t] = 0.f;
  for (int j = 0; j < 384; j += 16) {
#pragma unroll
    for (int t = 0; t < 16; ++t)
      s[t] = __fadd_rn(__fmul_rn(x[j + t], c[j + t]), s[t]);
  }
  float w0 = __fadd_rn(__fadd_rn(s[0], s[4]), __fadd_rn(s[8],  s[12]));
  float w1 = __fadd_rn(__fadd_rn(s[1], s[5]), __fadd_rn(s[9],  s[13]));
  float w2 = __fadd_rn(__fadd_rn(s[2], s[6]), __fadd_rn(s[10], s[14]));
  float w3 = __fadd_rn(__fadd_rn(s[3], s[7]), __fadd_rn(s[11], s[15]));
  return __fadd_rn(__fadd_rn(w0, w1), __fadd_rn(w2, w3));
}

// ---------------- prep: codebook norms (3 blocks) + bf16-split (144 blocks) --
__global__ __launch_bounds__(256) void prep_kernel(const float* __restrict__ c0,
                                                   const float* __restrict__ c1,
                                                   const float* __restrict__ c2,
                                                   float* __restrict__ e2,
                                                   double* __restrict__ delta,
                                                   short* __restrict__ fragbase) {
  int bid = blockIdx.x;
  if (bid < 3) {
    const float* cb = (bid == 0) ? c0 : ((bid == 1) ? c1 : c2);
    e2[bid * KN + threadIdx.x] = emu_sq_pairwise384(cb + (size_t)threadIdx.x * DD);
    if (threadIdx.x == 0) delta[bid] = 0.0;
    return;
  }
  int sb = bid - 3;                 // 0..143
  int lvl = sb / 48;
  int blk48 = sb - lvl * 48;
  const float* cb = (lvl == 0) ? c0 : ((lvl == 1) ? c1 : c2);
  short* frag = fragbase + (size_t)lvl * 196608;
  int gid = blk48 * 256 + threadIdx.x;            // 12288 = 256 entries * 48 groups
  int e = gid / 48;
  int g = gid - e * 48;
  const float4* s4 = reinterpret_cast<const float4*>(cb) + (size_t)e * 96 + g * 2;
  float4 v0 = s4[0], v1 = s4[1];
  float xs[8] = {v0.x, v0.y, v0.z, v0.w, v1.x, v1.y, v1.z, v1.w};
  short h[8], l[8];
#pragma unroll
  for (int i = 0; i < 8; ++i) {
    h[i] = (short)f2bf_rne(xs[i]);
    float hf = __uint_as_float((unsigned)(unsigned short)h[i] << 16);
    l[i] = (short)f2bf_rne(xs[i] - hf);
  }
  int c = g >> 2, rem = g & 3, ks = rem >> 1, hs = rem & 1;
  int t = e >> 5, lane = (e & 31) + (hs << 5);
  size_t blk = (((size_t)(c * 8 + t) * 2 + ks) * 2);
  short* dh = frag + blk * 512 + lane * 8;
  short* dl = dh + 512;
  *reinterpret_cast<bf16x8*>(dh) = *reinterpret_cast<const bf16x8*>(h);
  *reinterpret_cast<bf16x8*>(dl) = *reinterpret_cast<const bf16x8*>(l);
}

// ---------------- phase 1: merged 3-level MFMA GEMM + argmin + flag ---------
__global__ __launch_bounds__(256) void vq_main(
    const float* __restrict__ X0, const float* __restrict__ X1, const float* __restrict__ X2,
    const float* __restrict__ C0, const float* __restrict__ C1, const float* __restrict__ C2,
    const short* __restrict__ FRAGBASE,
    const float* __restrict__ E2A,
    float* __restrict__ QBASE,          // q0; q1,q2 contiguous after
    float* __restrict__ IDXBASE,        // idx0; idx1,idx2 contiguous after
    unsigned char* __restrict__ FLAGBASE,
    double* __restrict__ PART,          // indexed by blockIdx.x (levels concatenated)
    int nb0, int nb1)
{
  __shared__ __align__(16) short cb_lds[16384];  // 32KB, [t(8)][ks(2)][hl(2)] 1KB blocks
  __shared__ __align__(16) short x_lds[4224];    // 8.25KB, 8 blocks x 528 shorts
  __shared__ int idx_s[TM];
  __shared__ float xx_s[TM];
  __shared__ float cand_b1[2][TM];
  __shared__ int   cand_i1[2][TM];
  __shared__ float cand_b2[2][TM];

  const int bid = blockIdx.x;
  int lvl, lb;
  if (bid < nb0)            { lvl = 0; lb = bid; }
  else if (bid < nb0 + nb1) { lvl = 1; lb = bid - nb0; }
  else                      { lvl = 2; lb = bid - nb0 - nb1; }
  const float* X  = (lvl == 0) ? X0 : ((lvl == 1) ? X1 : X2);
  const float* CBF32 = (lvl == 0) ? C0 : ((lvl == 1) ? C1 : C2);
  const short* CBFRAG = FRAGBASE + (size_t)lvl * 196608;
  const float* E2 = E2A + lvl * KN;
  const size_t rowbase = (lvl == 0) ? 0 : ((lvl == 1) ? (size_t)nb0 * TM
                                                      : (size_t)(nb0 + nb1) * TM);
  float* Q = QBASE + rowbase * DD;      // level rows contiguous in output
  float* IDXO = IDXBASE + rowbase;
  unsigned char* FLAG = FLAGBASE + rowbase;
  const size_t row0 = (size_t)lb * TM;

  const float4* X4 = reinterpret_cast<const float4*>(X);

  f32x16 acc[4];
  {
    f32x16 z;
#pragma unroll
    for (int i = 0; i < 16; ++i) z[i] = 0.f;
#pragma unroll
    for (int ct = 0; ct < 4; ++ct) acc[ct] = z;
  }
  const int tid  = threadIdx.x;
  const int wid  = tid >> 6, lane = tid & 63;
  const int lr   = lane & 31, hi = lane >> 5;
  const int wr   = wid >> 1, wc = wid & 1;
  float xx0 = 0.f, xx1 = 0.f;   // row-norm partials (rows tid>>3 and (tid>>3)+32)

#pragma unroll 1
  for (int c = 0; c < 12; ++c) {
    // stage CB chunk: async global->LDS, 8 x 16B per thread, linear
    {
      const char* gsrc = (const char*)CBFRAG + (size_t)c * 32768 + tid * 16;
#pragma unroll
      for (int s = 0; s < 8; ++s)
        g2lds16(gsrc + s * 4096, (char*)cb_lds + tid * 16 + s * 4096);
    }
    // stage X chunk: 64 rows x 32 k fp32 -> bf16 h/l, fragment-ordered, padded
#pragma unroll
    for (int i = 0; i < 2; ++i) {
      int idx = tid + i * 256;
      int r = idx >> 3, k4 = idx & 7;
      float4 v = X4[(row0 + (size_t)r) * DD4 + c * 8 + k4];
      float pp = v.x * v.x + v.y * v.y + v.z * v.z + v.w * v.w;
      if (i == 0) xx0 += pp; else xx1 += pp;
      float xs[4] = {v.x, v.y, v.z, v.w};
      short h[4], l[4];
#pragma unroll
      for (int e = 0; e < 4; ++e) {
        h[e] = (short)f2bf_rne(xs[e]);
        float hf = __uint_as_float((unsigned)(unsigned short)h[e] << 16);
        l[e] = (short)f2bf_rne(xs[e] - hf);
      }
      int rt = r >> 5, ks = k4 >> 2, hs = (k4 >> 1) & 1;
      int off_h = ((rt * 2 + ks) * 2) * 528 + hs * 264 + (r & 31) * 8 + (k4 & 1) * 4;
      *reinterpret_cast<short4v*>(&x_lds[off_h])       = *reinterpret_cast<short4v*>(h);
      *reinterpret_cast<short4v*>(&x_lds[off_h + 528]) = *reinterpret_cast<short4v*>(l);
    }
    __syncthreads();

#pragma unroll 1
    for (int ks = 0; ks < 2; ++ks) {
      const int abase = ((wr * 2 + ks) * 2) * 528 + hi * 264 + lr * 8;
      bf16x8 ah = *reinterpret_cast<const bf16x8*>(&x_lds[abase]);
      bf16x8 al = *reinterpret_cast<const bf16x8*>(&x_lds[abase + 528]);
      const bf16x8* bb = reinterpret_cast<const bf16x8*>(cb_lds);
#pragma unroll
      for (int ct = 0; ct < 4; ++ct) {
        int t = wc * 4 + ct;
        bf16x8 bh = bb[((t * 2 + ks) * 2 + 0) * 64 + lane];
        bf16x8 bl = bb[((t * 2 + ks) * 2 + 1) * 64 + lane];
        acc[ct] = __builtin_amdgcn_mfma_f32_32x32x16_bf16(ah, bh, acc[ct], 0, 0, 0);
        acc[ct] = __builtin_amdgcn_mfma_f32_32x32x16_bf16(ah, bl, acc[ct], 0, 0, 0);
        acc[ct] = __builtin_amdgcn_mfma_f32_32x32x16_bf16(al, bh, acc[ct], 0, 0, 0);
      }
    }
    __syncthreads();
  }

  // ---- row norms: reduce 8-thread groups, park in LDS ----
#pragma unroll
  for (int m = 1; m < 8; m <<= 1) {
    xx0 += __shfl_xor(xx0, m);
    xx1 += __shfl_xor(xx1, m);
  }
  if ((lane & 7) == 0) {
    xx_s[tid >> 3]        = xx0;
    xx_s[(tid >> 3) + 32] = xx1;
  }

  // ---- argmin epilogue: D layout col=lane&31, row=(v&3)+8*(v>>2)+4*hi ----
  float e2v[4];
#pragma unroll
  for (int ct = 0; ct < 4; ++ct) e2v[ct] = E2[wc * 128 + ct * 32 + lr];

#pragma unroll
  for (int v = 0; v < 16; ++v) {
    int rloc = (v & 3) + 8 * (v >> 2) + 4 * hi;
    int row = wr * 32 + rloc;
    float b1 = 1e30f; int i1 = 0x7fffffff;
#pragma unroll
    for (int ct = 0; ct < 4; ++ct) {
      float sc = e2v[ct] - 2.0f * acc[ct][v];
      int col = wc * 128 + ct * 32 + lr;
      if (sc < b1) { b1 = sc; i1 = col; }
    }
#pragma unroll
    for (int m = 1; m < 32; m <<= 1) {     // within 32-lane halves (hi preserved)
      float ob = __shfl_xor(b1, m);
      int   oi = __shfl_xor(i1, m);
      if (ob < b1 || (ob == b1 && oi < i1)) { b1 = ob; i1 = oi; }
    }
    float b2 = 1e30f;
#pragma unroll
    for (int ct = 0; ct < 4; ++ct) {
      float sc = e2v[ct] - 2.0f * acc[ct][v];
      int col = wc * 128 + ct * 32 + lr;
      if (col != i1 && sc < b2) b2 = sc;
    }
#pragma unroll
    for (int m = 1; m < 32; m <<= 1) {
      float ob = __shfl_xor(b2, m);
      if (ob < b2) b2 = ob;
    }
    if (lr == 0) {
      cand_b1[wc][row] = b1; cand_i1[wc][row] = i1; cand_b2[wc][row] = b2;
    }
  }
  __syncthreads();

  // merge col-halves; idx/flag; per-row loss = xx + b1
  double lrow = 0.0;
  if (tid < TM) {
    float a1 = cand_b1[0][tid], a2 = cand_b2[0][tid];
    int   ai = cand_i1[0][tid];
    float c1 = cand_b1[1][tid], c2 = cand_b2[1][tid];
    int   ci = cand_i1[1][tid];
    float b1; int i1; float b2;
    if (c1 < a1 || (c1 == a1 && ci < ai)) {
      b1 = c1; i1 = ci; b2 = (a1 < c2) ? a1 : c2;
    } else {
      b1 = a1; i1 = ai; b2 = (c1 < a2) ? c1 : a2;
    }
    idx_s[tid] = i1;
    IDXO[row0 + tid] = (float)i1;
    FLAG[row0 + tid] = (b2 - b1 < FLAG_MARGIN) ? 1 : 0;
    lrow = (double)xx_s[tid] + (double)b1;
  }
  if (tid < 64) {
#pragma unroll
    for (int m = 1; m < 64; m <<= 1) lrow += __shfl_xor(lrow, m);
    if (tid == 0) PART[bid] = lrow;
  }
  __syncthreads();

  // ---- output: q = cb[idx] (pure gather+write; no X re-read) ----
  const float4* CB4 = reinterpret_cast<const float4*>(CBF32);
  float4* Q4 = reinterpret_cast<float4*>(Q);
  for (int i = tid; i < TM * DD4; i += 256) {
    int r = i / DD4;
    int cc = i - r * DD4;
    Q4[(row0 + (size_t)r) * DD4 + cc] = CB4[(size_t)idx_s[r] * DD4 + cc];
  }
}

// ---------------- phase 2: numpy-exact refine, all 3 levels, one launch -----
__global__ __launch_bounds__(256) void vq_refine(
    const float* __restrict__ X0, const float* __restrict__ X1, const float* __restrict__ X2,
    const float* __restrict__ C0, const float* __restrict__ C1, const float* __restrict__ C2,
    const float* __restrict__ E2A,
    const unsigned char* __restrict__ F0, const unsigned char* __restrict__ F1,
    const unsigned char* __restrict__ F2,
    int r0, int r1, int r2,
    float* __restrict__ Q0, float* __restrict__ Q1, float* __restrict__ Q2,
    float* __restrict__ I0, float* __restrict__ I1, float* __restrict__ I2,
    double* __restrict__ DELTA)
{
  const int lane   = threadIdx.x & 63;
  const int gwave  = (blockIdx.x * blockDim.x + threadIdx.x) >> 6;
  const int nwaves = (gridDim.x * blockDim.x) >> 6;
  const int ntot = r0 + r1 + r2;

  for (int base = gwave * 64; base < ntot; base += nwaves * 64) {
    int lvl, lb;
    const float *X, *CB; const unsigned char* FLAG; float *Q, *IDXO;
    if (base < r0)           { lvl = 0; lb = base;            X = X0; CB = C0; FLAG = F0; Q = Q0; IDXO = I0; }
    else if (base < r0 + r1) { lvl = 1; lb = base - r0;       X = X1; CB = C1; FLAG = F1; Q = Q1; IDXO = I1; }
    else                     { lvl = 2; lb = base - r0 - r1;  X = X2; CB = C2; FLAG = F2; Q = Q2; IDXO = I2; }
    const float* E2EMU = E2A + lvl * KN;

    unsigned char f = FLAG[lb + lane];
    unsigned long long mask = __ballot(f != 0);
    while (mask) {
      int bit = __ffsll((long long)mask) - 1;
      mask &= mask - 1;
      const int r = lb + bit;
      const float* xr = X + (size_t)r * DD;
      const float xx = emu_sq_pairwise384(xr);

      float best = 1e30f; int bidx = 0x7fffffff;
#pragma unroll
      for (int t = 0; t < 4; ++t) {
        int k = lane * 4 + t;
        const float* ck = CB + (size_t)k * DD;
        float E = emu_dot384_np(xr, ck);
        float s = __fadd_rn(__fsub_rn(xx, __fmul_rn(2.0f, E)), E2EMU[k]);
        if (s < best || (s == best && k < bidx)) { best = s; bidx = k; }
      }
#pragma unroll
      for (int m = 1; m < 64; m <<= 1) {
        float ob = __shfl_xor(best, m);
        int   oi = __shfl_xor(bidx, m);
        if (ob < best || (ob == best && oi < bidx)) { best = ob; bidx = oi; }
      }

      const int old = (int)IDXO[r];
      if (bidx != old) {
        const float* cn = CB + (size_t)bidx * DD;
        const float* co = CB + (size_t)old * DD;
        double dl = 0.0;
        for (int d = lane; d < DD; d += 64) {
          float xv = xr[d];
          float qn = cn[d], qo = co[d];
          Q[(size_t)r * DD + d] = qn;
          double en = (double)qn - (double)xv;
          double eo = (double)qo - (double)xv;
          dl += en * en - eo * eo;
        }
#pragma unroll
        for (int m = 1; m < 64; m <<= 1) dl += __shfl_xor(dl, m);
        if (lane == 0) {
          atomicAdd(DELTA + lvl, dl);
          IDXO[r] = (float)bidx;
        }
      }
    }
  }
}

// ---------------- loss finalize ----------------
__global__ void finalize_kernel(const double* __restrict__ p0, int n0, double w0,
                                const double* __restrict__ p1, int n1, double w1,
                                const double* __restrict__ p2, int n2, double w2,
                                const double* __restrict__ delta,
                                float* __restrict__ out) {
  __shared__ double red[4];
  int tid = threadIdx.x;
  double s0 = 0.0, s1 = 0.0, s2 = 0.0;
  for (int i = tid; i < n0; i += 256) s0 += p0[i];
  for (int i = tid; i < n1; i += 256) s1 += p1[i];
  for (int i = tid; i < n2; i += 256) s2 += p2[i];
  double v = s0 * w0 + s1 * w1 + s2 * w2;
#pragma unroll
  for (int m = 1; m < 64; m <<= 1) v += __shfl_xor(v, m);
  if ((tid & 63) == 0) red[tid >> 6] = v;
  __syncthreads();
  if (tid == 0)
    out[0] = (float)(red[0] + red[1] + red[2] + red[3]
                     + delta[0] * w0 + delta[1] * w1 + delta[2] * w2);
}

extern "C" void kernel_launch(void* const* d_in, const int* in_sizes, int n_in,
                              void* d_out, int out_size, void* d_ws, size_t ws_size,
                              hipStream_t stream) {
  const float* l0  = (const float*)d_in[0];
  const float* l1  = (const float*)d_in[1];
  const float* l2  = (const float*)d_in[2];
  const float* cb0 = (const float*)d_in[3];
  const float* cb1 = (const float*)d_in[4];
  const float* cb2 = (const float*)d_in[5];

  const size_t n_q0 = (size_t)in_sizes[0];
  const size_t n_q1 = (size_t)in_sizes[1];
  const size_t n_q2 = (size_t)in_sizes[2];
  const int r0 = (int)(n_q0 / DD);   // 65536
  const int r1 = (int)(n_q1 / DD);   // 262144
  const int r2 = (int)(n_q2 / DD);   // 262144

  float* out   = (float*)d_out;
  float* q0    = out;
  float* q1    = q0 + n_q0;
  float* q2    = q1 + n_q1;
  float* lossp = q2 + n_q2;
  float* idx0  = lossp + 1;
  float* idx1  = idx0 + r0;
  float* idx2  = idx1 + r1;

  // ws layout
  float*  e2    = (float*)d_ws;                          // 3*256 f32
  double* part  = (double*)((char*)d_ws + 4096);         // 9216 doubles
  double* delta = (double*)((char*)d_ws + 4096 + 73728);
  unsigned char* flag0 = (unsigned char*)d_ws + 4096 + 73728 + 1024;
  unsigned char* flag1 = flag0 + r0;
  unsigned char* flag2 = flag1 + r1;
  short* cbf0 = (short*)((char*)d_ws + (1 << 20));       // 3 x 384 KiB

  const int nb0 = r0 / TM, nb1 = r1 / TM, nb2 = r2 / TM;  // 1024/4096/4096
  double* p0 = part;
  double* p1 = p0 + nb0;
  double* p2 = p1 + nb1;

  prep_kernel<<<147, 256, 0, stream>>>(cb0, cb1, cb2, e2, delta, cbf0);

  vq_main<<<nb0 + nb1 + nb2, 256, 0, stream>>>(
      l0, l1, l2, cb0, cb1, cb2, cbf0, e2,
      q0, idx0, flag0, part, nb0, nb1);

  vq_refine<<<512, 256, 0, stream>>>(l0, l1, l2, cb0, cb1, cb2, e2,
                                     flag0, flag1, flag2, r0, r1, r2,
                                     q0, q1, q2, idx0, idx1, idx2, delta);

  const double w0 = 0.05 / ((double)r0 * DD);
  const double w1 = 0.25 / ((double)r1 * DD);
  const double w2 = 0.60 / ((double)r2 * DD);
  finalize_kernel<<<1, 256, 0, stream>>>(p0, nb0, w0, p1, nb1, w1, p2, nb2, w2,
                                         delta, lossp);
}